// Round 5
// baseline (1411.941 us; speedup 1.0000x reference)
//
#include <hip/hip_runtime.h>
#include <hip/hip_bf16.h>
#include <cstdint>

#define NEG_SLOPE 0.2f

// ================= CSR build =================
__global__ void k_init_counts(int* __restrict__ counts, int n) {
  int i = blockIdx.x * blockDim.x + threadIdx.x;
  if (i < n) counts[i] = 1;  // self loop
}

__global__ void k_hist(const int* __restrict__ dst, int* __restrict__ counts, int e) {
  int i = blockIdx.x * blockDim.x + threadIdx.x;
  if (i < e) atomicAdd(&counts[dst[i]], 1);
}

__global__ void k_scan(const int* __restrict__ counts, int* __restrict__ rowptr, int n) {
  __shared__ int ssum[256];
  int tid = threadIdx.x;
  int per = (n + 255) >> 8;
  int beg = tid * per;
  int end = beg + per; if (end > n) end = n; if (beg > n) beg = n;
  int s = 0;
  for (int i = beg; i < end; ++i) s += counts[i];
  ssum[tid] = s;
  __syncthreads();
  for (int off = 1; off < 256; off <<= 1) {
    int t = (tid >= off) ? ssum[tid - off] : 0;
    __syncthreads();
    ssum[tid] += t;
    __syncthreads();
  }
  int run = (tid > 0) ? ssum[tid - 1] : 0;
  if (tid == 0) rowptr[0] = 0;
  for (int i = beg; i < end; ++i) { run += counts[i]; rowptr[i + 1] = run; }
}

__global__ void k_init_csr(const int* __restrict__ rowptr, int* __restrict__ cursor,
                           int* __restrict__ csr_src, int n) {
  int i = blockIdx.x * blockDim.x + threadIdx.x;
  if (i < n) { int r = rowptr[i]; csr_src[r] = i; cursor[i] = r + 1; }
}

__global__ void k_fill(const int* __restrict__ src, const int* __restrict__ dst,
                       int* __restrict__ cursor, int* __restrict__ csr_src, int e) {
  int i = blockIdx.x * blockDim.x + threadIdx.x;
  if (i < e) { int p = atomicAdd(&cursor[dst[i]], 1); csr_src[p] = src[i]; }
}

// ================= fp32 tiled GEMM: C = A(MxK) @ B(KxN) =================
// BM=BN=64, BK=16, 256 threads, 4x4 per thread. N,K multiples of 64/16.
__global__ void k_gemm(const float* __restrict__ A, const float* __restrict__ B,
                       float* __restrict__ C, int M, int N, int K) {
  __shared__ float As[16][68];  // transposed A tile, padded
  __shared__ float Bs[16][64];
  int tid = threadIdx.x;
  int tn = tid & 15;        // col group 0..15
  int tm = tid >> 4;        // row group 0..15
  int row0 = blockIdx.y * 64;
  int col0 = blockIdx.x * 64;
  int arow = tid >> 2, ak = (tid & 3) * 4;   // A-load mapping
  int brow = tid >> 4, bcol = (tid & 15) * 4; // B-load mapping
  float acc[4][4] = {};
  for (int k0 = 0; k0 < K; k0 += 16) {
    float4 av = make_float4(0.f, 0.f, 0.f, 0.f);
    int gr = row0 + arow;
    if (gr < M) av = *reinterpret_cast<const float4*>(A + (size_t)gr * K + k0 + ak);
    As[ak + 0][arow] = av.x; As[ak + 1][arow] = av.y;
    As[ak + 2][arow] = av.z; As[ak + 3][arow] = av.w;
    float4 bv = *reinterpret_cast<const float4*>(B + (size_t)(k0 + brow) * N + col0 + bcol);
    *reinterpret_cast<float4*>(&Bs[brow][bcol]) = bv;
    __syncthreads();
#pragma unroll
    for (int k = 0; k < 16; ++k) {
      float4 av2 = *reinterpret_cast<const float4*>(&As[k][tm * 4]);
      float4 bv2 = *reinterpret_cast<const float4*>(&Bs[k][tn * 4]);
      float ar[4] = {av2.x, av2.y, av2.z, av2.w};
      float br[4] = {bv2.x, bv2.y, bv2.z, bv2.w};
#pragma unroll
      for (int i = 0; i < 4; ++i)
#pragma unroll
        for (int j = 0; j < 4; ++j)
          acc[i][j] += ar[i] * br[j];
    }
    __syncthreads();
  }
#pragma unroll
  for (int i = 0; i < 4; ++i) {
    int gr = row0 + tm * 4 + i;
    if (gr < M) {
      float4 o = make_float4(acc[i][0], acc[i][1], acc[i][2], acc[i][3]);
      *reinterpret_cast<float4*>(C + (size_t)gr * N + col0 + tn * 4) = o;
    }
  }
}

// ================= alpha: per (node, head) wave dot =================
template <int H, int CH>
__global__ void k_alpha(const float* __restrict__ h, const float* __restrict__ a_src,
                        const float* __restrict__ a_dst, float* __restrict__ as,
                        float* __restrict__ ad, int total /* n*H */) {
  int wid = (blockIdx.x * blockDim.x + threadIdx.x) >> 6;
  int lane = threadIdx.x & 63;
  if (wid >= total) return;
  int head = wid % H;
  const float* hp = h + (size_t)wid * CH;  // (n,H,CH) flat: wid = node*H+head
  float s1 = 0.f, s2 = 0.f;
  for (int c = lane; c < CH; c += 64) {
    float v = hp[c];
    s1 += v * a_src[head * CH + c];
    s2 += v * a_dst[head * CH + c];
  }
#pragma unroll
  for (int off = 32; off; off >>= 1) {
    s1 += __shfl_down(s1, off);
    s2 += __shfl_down(s2, off);
  }
  if (lane == 0) { as[wid] = s1; ad[wid] = s2; }
}

// ================= fused edge-softmax + aggregate (per dst node) =================
// CT = total channels (H*CH). block = CT threads. ACT: 0 none, 1 PReLU.
template <int CT, int H, int CH, int ACT>
__global__ void k_aggregate(const float* __restrict__ h, const float* __restrict__ as,
                            const float* __restrict__ ad, const int* __restrict__ rowptr,
                            const int* __restrict__ csr_src, const float* __restrict__ bias,
                            const float* __restrict__ prelu_a, float* __restrict__ out) {
  int node = blockIdx.x;
  int c = threadIdx.x;
  int head = c / CH;
  int beg = rowptr[node], end = rowptr[node + 1];
  float adv = ad[node * H + head];
  // pass 1: per-head max of leaky_relu(as+ad)
  float m = -1e30f;
  for (int i = beg; i < end; ++i) {
    int s = csr_src[i];
    float e = as[s * H + head] + adv;
    e = (e >= 0.f) ? e : NEG_SLOPE * e;
    m = fmaxf(m, e);
  }
  // pass 2: weighted sum
  float denom = 0.f, acc = 0.f;
  for (int i = beg; i < end; ++i) {
    int s = csr_src[i];
    float e = as[s * H + head] + adv;
    e = (e >= 0.f) ? e : NEG_SLOPE * e;
    float w = __expf(e - m);
    denom += w;
    acc += w * h[(size_t)s * CT + c];
  }
  float o = acc / (denom + 1e-16f) + bias[c];
  if (ACT) { float a = prelu_a[0]; o = (o >= 0.f) ? o : a * o; }
  out[(size_t)node * CT + c] = o;
}

// ================= launch =================
extern "C" void kernel_launch(void* const* d_in, const int* in_sizes, int n_in,
                              void* d_out, int out_size, void* d_ws, size_t ws_size,
                              hipStream_t stream) {
  const float* x      = (const float*)d_in[0];
  const int*   ei     = (const int*)d_in[1];
  const float* W1     = (const float*)d_in[2];
  const float* a_s1   = (const float*)d_in[3];
  const float* a_d1   = (const float*)d_in[4];
  const float* b1     = (const float*)d_in[5];
  const float* prelu  = (const float*)d_in[6];
  const float* W2     = (const float*)d_in[7];
  const float* a_s2   = (const float*)d_in[8];
  const float* a_d2   = (const float*)d_in[9];
  const float* b2     = (const float*)d_in[10];
  const float* Wd     = (const float*)d_in[11];
  const float* a_sd   = (const float*)d_in[12];
  const float* a_dd   = (const float*)d_in[13];
  const float* bd     = (const float*)d_in[14];

  const int N = in_sizes[0] / 256;   // 50000
  const int E = in_sizes[1] / 2;     // 400000
  const int* e_src = ei;
  const int* e_dst = ei + E;

  float* z    = (float*)d_out;           // N*256
  float* xhat = z + (size_t)N * 256;     // N*256

  // workspace layout (~107 MB): h_buf N*512 + small arrays.
  // out1 (layer-1 output, N*512) reuses d_out: it is dead before z/xhat are
  // written (last read = layer-2 GEMM, which precedes layer-2 aggregation).
  float* h_buf = (float*)d_ws;                    // N*512 (reused per layer)
  float* out1  = z;                               // N*512 scratch in d_out
  float* alpS  = h_buf + (size_t)N * 512;         // N*4 max
  float* alpD  = alpS + (size_t)N * 4;
  int* rowptr  = (int*)(alpD + (size_t)N * 4);    // N+1
  int* csr     = rowptr + (N + 1);                // E+N
  int* cursor  = csr + (E + N);                   // N
  int* counts  = cursor + N;                      // N

  const int B = 256;
  const int gN = (N + B - 1) / B;
  const int gE = (E + B - 1) / B;

  // ---- CSR (built once, reused for all 3 layers) ----
  k_init_counts<<<gN, B, 0, stream>>>(counts, N);
  k_hist<<<gE, B, 0, stream>>>(e_dst, counts, E);
  k_scan<<<1, B, 0, stream>>>(counts, rowptr, N);
  k_init_csr<<<gN, B, 0, stream>>>(rowptr, cursor, csr, N);
  k_fill<<<gE, B, 0, stream>>>(e_src, e_dst, cursor, csr, E);

  // ---- layer 1: D=256 -> 4x128 concat, PReLU ----
  {
    dim3 grid(512 / 64, (N + 63) / 64);
    k_gemm<<<grid, B, 0, stream>>>(x, W1, h_buf, N, 512, 256);
    int waves = N * 4;
    k_alpha<4, 128><<<(waves * 64 + B - 1) / B, B, 0, stream>>>(h_buf, a_s1, a_d1, alpS, alpD, waves);
    k_aggregate<512, 4, 128, 1><<<N, 512, 0, stream>>>(h_buf, alpS, alpD, rowptr, csr, b1, prelu, out1);
  }

  // ---- layer 2: 512 -> 256, 1 head ----
  {
    dim3 grid(256 / 64, (N + 63) / 64);
    k_gemm<<<grid, B, 0, stream>>>(out1, W2, h_buf, N, 256, 512);
    int waves = N;
    k_alpha<1, 256><<<(waves * 64 + B - 1) / B, B, 0, stream>>>(h_buf, a_s2, a_d2, alpS, alpD, waves);
    k_aggregate<256, 1, 256, 0><<<N, 256, 0, stream>>>(h_buf, alpS, alpD, rowptr, csr, b2, prelu, z);
  }

  // ---- decoder: 256 -> 256, 1 head ----
  {
    dim3 grid(256 / 64, (N + 63) / 64);
    k_gemm<<<grid, B, 0, stream>>>(z, Wd, h_buf, N, 256, 256);
    int waves = N;
    k_alpha<1, 256><<<(waves * 64 + B - 1) / B, B, 0, stream>>>(h_buf, a_sd, a_dd, alpS, alpD, waves);
    k_aggregate<256, 1, 256, 0><<<N, 256, 0, stream>>>(h_buf, alpS, alpD, rowptr, csr, bd, prelu, xhat);
  }
}

// Round 7
// 925.379 us; speedup vs baseline: 1.5258x; 1.5258x over previous
//
#include <hip/hip_runtime.h>
#include <hip/hip_bf16.h>
#include <cstdint>

#define NEG_SLOPE 0.2f

typedef _Float16 f16x8 __attribute__((ext_vector_type(8)));
typedef float f32x4 __attribute__((ext_vector_type(4)));

// ================= CSR build =================
__global__ void k_init_counts(int* __restrict__ counts, int n) {
  int i = blockIdx.x * blockDim.x + threadIdx.x;
  if (i < n) counts[i] = 1;  // self loop
}

__global__ void k_hist(const int* __restrict__ dst, int* __restrict__ counts, int e) {
  int i = blockIdx.x * blockDim.x + threadIdx.x;
  if (i < e) atomicAdd(&counts[dst[i]], 1);
}

__global__ void k_scan(const int* __restrict__ counts, int* __restrict__ rowptr, int n) {
  __shared__ int ssum[256];
  int tid = threadIdx.x;
  int per = (n + 255) >> 8;
  int beg = tid * per;
  int end = beg + per; if (end > n) end = n; if (beg > n) beg = n;
  int s = 0;
  for (int i = beg; i < end; ++i) s += counts[i];
  ssum[tid] = s;
  __syncthreads();
  for (int off = 1; off < 256; off <<= 1) {
    int t = (tid >= off) ? ssum[tid - off] : 0;
    __syncthreads();
    ssum[tid] += t;
    __syncthreads();
  }
  int run = (tid > 0) ? ssum[tid - 1] : 0;
  if (tid == 0) rowptr[0] = 0;
  for (int i = beg; i < end; ++i) { run += counts[i]; rowptr[i + 1] = run; }
}

__global__ void k_init_csr(const int* __restrict__ rowptr, int* __restrict__ cursor,
                           int* __restrict__ csr_src, int n) {
  int i = blockIdx.x * blockDim.x + threadIdx.x;
  if (i < n) { int r = rowptr[i]; csr_src[r] = i; cursor[i] = r + 1; }
}

__global__ void k_fill(const int* __restrict__ src, const int* __restrict__ dst,
                       int* __restrict__ cursor, int* __restrict__ csr_src, int e) {
  int i = blockIdx.x * blockDim.x + threadIdx.x;
  if (i < e) { int p = atomicAdd(&cursor[dst[i]], 1); csr_src[p] = src[i]; }
}

// ================= weight convert: W (KxN fp32) -> Wt (NxK fp16) =================
__global__ void k_w2h(const float* __restrict__ W, _Float16* __restrict__ Wt, int K, int N) {
  int i = blockIdx.x * blockDim.x + threadIdx.x;
  if (i < K * N) {
    int k = i / N, n = i - k * N;
    Wt[(size_t)n * K + k] = (_Float16)W[i];
  }
}

// ================= fp16 MFMA GEMM: C(f16) = A(MxK) @ Bt^T (Bt is NxK) ==========
// BM=128, BN=64, BK=64. 256 threads = 4 waves (2x2), per-wave out 64x32.
// LDS rows padded to 72 f16 (144 B): frag reads 2-way (free).
template <bool A_F32>
__global__ __launch_bounds__(256) void k_gemm_f16(
    const void* __restrict__ Av, const _Float16* __restrict__ Bt,
    _Float16* __restrict__ C, int M, int N, int K) {
  __shared__ _Float16 As[128 * 72];
  __shared__ _Float16 Bs[64 * 72];
  const int tid  = threadIdx.x;
  const int lane = tid & 63;
  const int wid  = tid >> 6;
  const int wm = wid >> 1, wn = wid & 1;
  const int row0 = blockIdx.y * 128, col0 = blockIdx.x * 64;
  const int l15 = lane & 15, l16 = lane >> 4;
  const int srow = tid >> 3;       // 0..31
  const int skc  = (tid & 7) * 8;  // f16 offset in 0..63

  f32x4 acc[4][2] = {};

  for (int k0 = 0; k0 < K; k0 += 64) {
    // stage A: 128 rows x 64 k
#pragma unroll
    for (int p = 0; p < 4; ++p) {
      int r = p * 32 + srow;
      int gr = row0 + r; if (gr > M - 1) gr = M - 1;
      _Float16 tmp[8];
      if constexpr (A_F32) {
        const float* src = (const float*)Av + (size_t)gr * K + k0 + skc;
        float4 v0 = ((const float4*)src)[0];
        float4 v1 = ((const float4*)src)[1];
        tmp[0] = (_Float16)v0.x; tmp[1] = (_Float16)v0.y;
        tmp[2] = (_Float16)v0.z; tmp[3] = (_Float16)v0.w;
        tmp[4] = (_Float16)v1.x; tmp[5] = (_Float16)v1.y;
        tmp[6] = (_Float16)v1.z; tmp[7] = (_Float16)v1.w;
      } else {
        const _Float16* src = (const _Float16*)Av + (size_t)gr * K + k0 + skc;
        *(uint4*)tmp = *(const uint4*)src;
      }
      *(uint4*)&As[r * 72 + skc] = *(uint4*)tmp;
    }
    // stage B: 64 out-cols x 64 k (Bt row-major NxK)
#pragma unroll
    for (int p = 0; p < 2; ++p) {
      int n = p * 32 + srow;
      const _Float16* src = Bt + (size_t)(col0 + n) * K + k0 + skc;
      *(uint4*)&Bs[n * 72 + skc] = *(const uint4*)src;
    }
    __syncthreads();
#pragma unroll
    for (int ks = 0; ks < 2; ++ks) {
      f16x8 bfrag[2];
#pragma unroll
      for (int nr = 0; nr < 2; ++nr)
        bfrag[nr] = *(const f16x8*)&Bs[(wn * 32 + nr * 16 + l15) * 72 + ks * 32 + l16 * 8];
#pragma unroll
      for (int mr = 0; mr < 4; ++mr) {
        f16x8 afrag = *(const f16x8*)&As[(wm * 64 + mr * 16 + l15) * 72 + ks * 32 + l16 * 8];
#pragma unroll
        for (int nr = 0; nr < 2; ++nr)
          acc[mr][nr] = __builtin_amdgcn_mfma_f32_16x16x32_f16(afrag, bfrag[nr], acc[mr][nr], 0, 0, 0);
      }
    }
    __syncthreads();
  }
  // epilogue: C/D map col=lane&15, row=(lane>>4)*4+reg
#pragma unroll
  for (int mr = 0; mr < 4; ++mr) {
#pragma unroll
    for (int j = 0; j < 4; ++j) {
      int rg = row0 + wm * 64 + mr * 16 + l16 * 4 + j;
      if (rg < M) {
#pragma unroll
        for (int nr = 0; nr < 2; ++nr) {
          int cg = col0 + wn * 32 + nr * 16 + l15;
          C[(size_t)rg * N + cg] = (_Float16)acc[mr][nr][j];
        }
      }
    }
  }
}

// ================= alpha: per (node, head) wave dot over fp16 h =================
template <int H, int CH>
__global__ void k_alpha(const _Float16* __restrict__ h, const float* __restrict__ a_src,
                        const float* __restrict__ a_dst, float* __restrict__ as,
                        float* __restrict__ ad, int total /* n*H */) {
  int wid = (blockIdx.x * blockDim.x + threadIdx.x) >> 6;
  int lane = threadIdx.x & 63;
  if (wid >= total) return;
  int head = wid % H;
  const _Float16* hp = h + (size_t)wid * CH;
  float s1 = 0.f, s2 = 0.f;
  for (int c = lane; c < CH; c += 64) {
    float v = (float)hp[c];
    s1 += v * a_src[head * CH + c];
    s2 += v * a_dst[head * CH + c];
  }
#pragma unroll
  for (int off = 32; off; off >>= 1) {
    s1 += __shfl_down(s1, off);
    s2 += __shfl_down(s2, off);
  }
  if (lane == 0) { as[wid] = s1; ad[wid] = s2; }
}

// ================= per-edge normalized attention weights =================
// one thread per (node, head); edges of a node are csr[rowptr[n]..rowptr[n+1])
template <int H>
__global__ void k_att(const float* __restrict__ as, const float* __restrict__ ad,
                      const int* __restrict__ rowptr, const int* __restrict__ csr,
                      float* __restrict__ att, int n) {
  int t = blockIdx.x * blockDim.x + threadIdx.x;
  if (t >= n * H) return;
  int node = t / H, head = t - node * H;
  int beg = rowptr[node], end = rowptr[node + 1];
  float adv = ad[t];
  float m = -1e30f;
  for (int i = beg; i < end; ++i) {
    float e = as[csr[i] * H + head] + adv;
    e = (e >= 0.f) ? e : NEG_SLOPE * e;
    m = fmaxf(m, e);
  }
  float denom = 0.f;
  for (int i = beg; i < end; ++i) {
    float e = as[csr[i] * H + head] + adv;
    e = (e >= 0.f) ? e : NEG_SLOPE * e;
    float w = __expf(e - m);
    att[i * H + head] = w;
    denom += w;
  }
  float inv = 1.f / (denom + 1e-16f);
  for (int i = beg; i < end; ++i) att[i * H + head] *= inv;
}

// ================= aggregation: out[n] = sum_e att[e] * h[src[e]] + bias ======
template <int CT, int H, int ACT, int WF, int WH>
__global__ void k_agg(const _Float16* __restrict__ h, const float* __restrict__ att,
                      const int* __restrict__ rowptr, const int* __restrict__ csr,
                      const float* __restrict__ bias, const float* __restrict__ prelu_a,
                      float* __restrict__ outf, _Float16* __restrict__ outh) {
  int node = blockIdx.x;
  int c = threadIdx.x;
  constexpr int CH = CT / H;
  int head = c / CH;
  int beg = rowptr[node], end = rowptr[node + 1];
  float acc = 0.f;
  for (int i = beg; i < end; ++i) {
    int s = csr[i];
    float w = att[i * H + head];
    acc += w * (float)h[(size_t)s * CT + c];
  }
  float o = acc + bias[c];
  if (ACT) { float a = prelu_a[0]; o = (o >= 0.f) ? o : a * o; }
  if (WF) outf[(size_t)node * CT + c] = o;
  if (WH) outh[(size_t)node * CT + c] = (_Float16)o;
}

// ================= launch =================
extern "C" void kernel_launch(void* const* d_in, const int* in_sizes, int n_in,
                              void* d_out, int out_size, void* d_ws, size_t ws_size,
                              hipStream_t stream) {
  const float* x      = (const float*)d_in[0];
  const int*   ei     = (const int*)d_in[1];
  const float* W1     = (const float*)d_in[2];
  const float* a_s1   = (const float*)d_in[3];
  const float* a_d1   = (const float*)d_in[4];
  const float* b1     = (const float*)d_in[5];
  const float* prelu  = (const float*)d_in[6];
  const float* W2     = (const float*)d_in[7];
  const float* a_s2   = (const float*)d_in[8];
  const float* a_d2   = (const float*)d_in[9];
  const float* b2     = (const float*)d_in[10];
  const float* Wd     = (const float*)d_in[11];
  const float* a_sd   = (const float*)d_in[12];
  const float* a_dd   = (const float*)d_in[13];
  const float* bd     = (const float*)d_in[14];

  const int N = in_sizes[0] / 256;   // 50000
  const int E = in_sizes[1] / 2;     // 400000
  const int* e_src = ei;
  const int* e_dst = ei + E;

  float* z    = (float*)d_out;           // N*256 fp32
  float* xhat = z + (size_t)N * 256;     // N*256 fp32

  // out1_h (layer-1 fp16 output, N*512 f16 = N*256 f32 bytes) lives in the
  // xhat half of d_out: dead after the layer-2 GEMM; xhat is written only by
  // the decoder's final aggregation. d_out is fully overwritten every call.
  _Float16* out1_h = (_Float16*)xhat;

  // ---- workspace (~62 MB) ----
  char* wp = (char*)d_ws;
  auto alloc = [&](size_t bytes) { char* p = wp; wp += (bytes + 15) & ~(size_t)15; return p; };
  _Float16* h_h  = (_Float16*)alloc((size_t)N * 512 * 2);  // h1 / h2 / h3
  float* alpS    = (float*)alloc((size_t)N * 4 * 4);
  float* alpD    = (float*)alloc((size_t)N * 4 * 4);
  float* att     = (float*)alloc((size_t)(E + N) * 4 * 4);
  int* rowptr    = (int*)alloc((size_t)(N + 1) * 4);
  int* csr       = (int*)alloc((size_t)(E + N) * 4);
  int* cursor    = (int*)alloc((size_t)N * 4);
  int* counts    = (int*)alloc((size_t)N * 4);
  _Float16* Wt1  = (_Float16*)alloc((size_t)512 * 256 * 2);
  _Float16* Wt2  = (_Float16*)alloc((size_t)256 * 512 * 2);
  _Float16* Wtd  = (_Float16*)alloc((size_t)256 * 256 * 2);

  const int B = 256;
  const int gN = (N + B - 1) / B;
  const int gE = (E + B - 1) / B;

  // ---- CSR (built once, reused for all 3 layers) ----
  k_init_counts<<<gN, B, 0, stream>>>(counts, N);
  k_hist<<<gE, B, 0, stream>>>(e_dst, counts, E);
  k_scan<<<1, B, 0, stream>>>(counts, rowptr, N);
  k_init_csr<<<gN, B, 0, stream>>>(rowptr, cursor, csr, N);
  k_fill<<<gE, B, 0, stream>>>(e_src, e_dst, cursor, csr, E);

  // ---- weight converts (fp32 KxN -> fp16 NxK) ----
  k_w2h<<<(256 * 512 + B - 1) / B, B, 0, stream>>>(W1, Wt1, 256, 512);
  k_w2h<<<(512 * 256 + B - 1) / B, B, 0, stream>>>(W2, Wt2, 512, 256);
  k_w2h<<<(256 * 256 + B - 1) / B, B, 0, stream>>>(Wd, Wtd, 256, 256);

  const int gy = (N + 127) / 128;

  // ---- layer 1: 256 -> 4x128 concat, PReLU ----
  {
    dim3 grid(512 / 64, gy);
    k_gemm_f16<true><<<grid, B, 0, stream>>>(x, Wt1, h_h, N, 512, 256);
    int tot = N * 4;
    k_alpha<4, 128><<<(tot * 64 + B - 1) / B, B, 0, stream>>>(h_h, a_s1, a_d1, alpS, alpD, tot);
    k_att<4><<<(tot + B - 1) / B, B, 0, stream>>>(alpS, alpD, rowptr, csr, att, N);
    k_agg<512, 4, 1, 0, 1><<<N, 512, 0, stream>>>(h_h, att, rowptr, csr, b1, prelu, nullptr, out1_h);
  }

  // ---- layer 2: 512 -> 256, 1 head; writes z (fp32 in d_out) ----
  {
    dim3 grid(256 / 64, gy);
    k_gemm_f16<false><<<grid, B, 0, stream>>>(out1_h, Wt2, h_h, N, 256, 512);
    k_alpha<1, 256><<<(N * 64 + B - 1) / B, B, 0, stream>>>(h_h, a_s2, a_d2, alpS, alpD, N);
    k_att<1><<<gN, B, 0, stream>>>(alpS, alpD, rowptr, csr, att, N);
    k_agg<256, 1, 0, 1, 0><<<N, 256, 0, stream>>>(h_h, att, rowptr, csr, b2, prelu, z, nullptr);
  }

  // ---- decoder: 256 -> 256, 1 head; reads z (fp32), writes xhat ----
  {
    dim3 grid(256 / 64, gy);
    k_gemm_f16<true><<<grid, B, 0, stream>>>(z, Wtd, h_h, N, 256, 256);
    k_alpha<1, 256><<<(N * 64 + B - 1) / B, B, 0, stream>>>(h_h, a_sd, a_dd, alpS, alpD, N);
    k_att<1><<<gN, B, 0, stream>>>(alpS, alpD, rowptr, csr, att, N);
    k_agg<256, 1, 0, 1, 0><<<N, 256, 0, stream>>>(h_h, att, rowptr, csr, bd, prelu, xhat, nullptr);
  }
}

// Round 9
// 750.026 us; speedup vs baseline: 1.8825x; 1.2338x over previous
//
#include <hip/hip_runtime.h>
#include <hip/hip_bf16.h>
#include <cstdint>

#define NEG_SLOPE 0.2f

typedef _Float16 f16x8 __attribute__((ext_vector_type(8)));
typedef float f32x4 __attribute__((ext_vector_type(4)));

union H2 { uint32_t u; _Float16 f[2]; };

// ================= CSR build =================
__global__ void k_init_counts(int* __restrict__ counts, int n) {
  int i = blockIdx.x * blockDim.x + threadIdx.x;
  if (i < n) counts[i] = 1;  // self loop
}

__global__ void k_hist(const int* __restrict__ dst, int* __restrict__ counts, int e) {
  int i = blockIdx.x * blockDim.x + threadIdx.x;
  if (i < e) atomicAdd(&counts[dst[i]], 1);
}

__global__ void k_scan(const int* __restrict__ counts, int* __restrict__ rowptr, int n) {
  __shared__ int ssum[256];
  int tid = threadIdx.x;
  int per = (n + 255) >> 8;
  int beg = tid * per;
  int end = beg + per; if (end > n) end = n; if (beg > n) beg = n;
  int s = 0;
  for (int i = beg; i < end; ++i) s += counts[i];
  ssum[tid] = s;
  __syncthreads();
  for (int off = 1; off < 256; off <<= 1) {
    int t = (tid >= off) ? ssum[tid - off] : 0;
    __syncthreads();
    ssum[tid] += t;
    __syncthreads();
  }
  int run = (tid > 0) ? ssum[tid - 1] : 0;
  if (tid == 0) rowptr[0] = 0;
  for (int i = beg; i < end; ++i) { run += counts[i]; rowptr[i + 1] = run; }
}

__global__ void k_init_csr(const int* __restrict__ rowptr, int* __restrict__ cursor,
                           int* __restrict__ csr_src, int n) {
  int i = blockIdx.x * blockDim.x + threadIdx.x;
  if (i < n) { int r = rowptr[i]; csr_src[r] = i; cursor[i] = r + 1; }
}

__global__ void k_fill(const int* __restrict__ src, const int* __restrict__ dst,
                       int* __restrict__ cursor, int* __restrict__ csr_src, int e) {
  int i = blockIdx.x * blockDim.x + threadIdx.x;
  if (i < e) { int p = atomicAdd(&cursor[dst[i]], 1); csr_src[p] = src[i]; }
}

// ================= weight convert: W (KxN fp32) -> Wt (NxK fp16) =================
__global__ void k_w2h(const float* __restrict__ W, _Float16* __restrict__ Wt, int K, int N) {
  int i = blockIdx.x * blockDim.x + threadIdx.x;
  if (i < K * N) {
    int k = i / N, n = i - k * N;
    Wt[(size_t)n * K + k] = (_Float16)W[i];
  }
}

// ================= fp16 MFMA GEMM: C(f16) = A(MxK) @ Bt^T (Bt is NxK) ==========
// BM=128, BN=64, BK=64. 256 threads = 4 waves (2x2), per-wave out 64x32.
template <bool A_F32>
__global__ __launch_bounds__(256) void k_gemm_f16(
    const void* __restrict__ Av, const _Float16* __restrict__ Bt,
    _Float16* __restrict__ C, int M, int N, int K) {
  __shared__ _Float16 As[128 * 72];
  __shared__ _Float16 Bs[64 * 72];
  const int tid  = threadIdx.x;
  const int lane = tid & 63;
  const int wid  = tid >> 6;
  const int wm = wid >> 1, wn = wid & 1;
  const int row0 = blockIdx.y * 128, col0 = blockIdx.x * 64;
  const int l15 = lane & 15, l16 = lane >> 4;
  const int srow = tid >> 3;       // 0..31
  const int skc  = (tid & 7) * 8;  // f16 offset in 0..63

  f32x4 acc[4][2] = {};

  for (int k0 = 0; k0 < K; k0 += 64) {
#pragma unroll
    for (int p = 0; p < 4; ++p) {
      int r = p * 32 + srow;
      int gr = row0 + r; if (gr > M - 1) gr = M - 1;
      _Float16 tmp[8];
      if constexpr (A_F32) {
        const float* src = (const float*)Av + (size_t)gr * K + k0 + skc;
        float4 v0 = ((const float4*)src)[0];
        float4 v1 = ((const float4*)src)[1];
        tmp[0] = (_Float16)v0.x; tmp[1] = (_Float16)v0.y;
        tmp[2] = (_Float16)v0.z; tmp[3] = (_Float16)v0.w;
        tmp[4] = (_Float16)v1.x; tmp[5] = (_Float16)v1.y;
        tmp[6] = (_Float16)v1.z; tmp[7] = (_Float16)v1.w;
      } else {
        const _Float16* src = (const _Float16*)Av + (size_t)gr * K + k0 + skc;
        *(uint4*)tmp = *(const uint4*)src;
      }
      *(uint4*)&As[r * 72 + skc] = *(uint4*)tmp;
    }
#pragma unroll
    for (int p = 0; p < 2; ++p) {
      int n = p * 32 + srow;
      const _Float16* src = Bt + (size_t)(col0 + n) * K + k0 + skc;
      *(uint4*)&Bs[n * 72 + skc] = *(const uint4*)src;
    }
    __syncthreads();
#pragma unroll
    for (int ks = 0; ks < 2; ++ks) {
      f16x8 bfrag[2];
#pragma unroll
      for (int nr = 0; nr < 2; ++nr)
        bfrag[nr] = *(const f16x8*)&Bs[(wn * 32 + nr * 16 + l15) * 72 + ks * 32 + l16 * 8];
#pragma unroll
      for (int mr = 0; mr < 4; ++mr) {
        f16x8 afrag = *(const f16x8*)&As[(wm * 64 + mr * 16 + l15) * 72 + ks * 32 + l16 * 8];
#pragma unroll
        for (int nr = 0; nr < 2; ++nr)
          acc[mr][nr] = __builtin_amdgcn_mfma_f32_16x16x32_f16(afrag, bfrag[nr], acc[mr][nr], 0, 0, 0);
      }
    }
    __syncthreads();
  }
#pragma unroll
  for (int mr = 0; mr < 4; ++mr) {
#pragma unroll
    for (int j = 0; j < 4; ++j) {
      int rg = row0 + wm * 64 + mr * 16 + l16 * 4 + j;
      if (rg < M) {
#pragma unroll
        for (int nr = 0; nr < 2; ++nr) {
          int cg = col0 + wn * 32 + nr * 16 + l15;
          C[(size_t)rg * N + cg] = (_Float16)acc[mr][nr][j];
        }
      }
    }
  }
}

// ================= alpha: per (node, head) wave dot over fp16 h =================
template <int H, int CH>
__global__ void k_alpha(const _Float16* __restrict__ h, const float* __restrict__ a_src,
                        const float* __restrict__ a_dst, float* __restrict__ as,
                        float* __restrict__ ad, int total /* n*H */) {
  int wid = (blockIdx.x * blockDim.x + threadIdx.x) >> 6;
  int lane = threadIdx.x & 63;
  if (wid >= total) return;
  int head = wid % H;
  const _Float16* hp = h + (size_t)wid * CH;
  float s1 = 0.f, s2 = 0.f;
  for (int c = lane; c < CH; c += 64) {
    float v = (float)hp[c];
    s1 += v * a_src[head * CH + c];
    s2 += v * a_dst[head * CH + c];
  }
#pragma unroll
  for (int off = 32; off; off >>= 1) {
    s1 += __shfl_down(s1, off);
    s2 += __shfl_down(s2, off);
  }
  if (lane == 0) { as[wid] = s1; ad[wid] = s2; }
}

// ================= per-edge normalized attention weights =================
template <int H>
__global__ void k_att(const float* __restrict__ as, const float* __restrict__ ad,
                      const int* __restrict__ rowptr, const int* __restrict__ csr,
                      float* __restrict__ att, int n) {
  int t = blockIdx.x * blockDim.x + threadIdx.x;
  if (t >= n * H) return;
  int node = t / H, head = t - node * H;
  int beg = rowptr[node], end = rowptr[node + 1];
  float adv = ad[t];
  float m = -1e30f;
  for (int i = beg; i < end; ++i) {
    float e = as[csr[i] * H + head] + adv;
    e = (e >= 0.f) ? e : NEG_SLOPE * e;
    m = fmaxf(m, e);
  }
  float denom = 0.f;
  for (int i = beg; i < end; ++i) {
    float e = as[csr[i] * H + head] + adv;
    e = (e >= 0.f) ? e : NEG_SLOPE * e;
    float w = __expf(e - m);
    att[i * H + head] = w;
    denom += w;
  }
  float inv = 1.f / (denom + 1e-16f);
  for (int i = beg; i < end; ++i) att[i * H + head] *= inv;
}

// ================= aggregation: out[n] = sum_e att[e] * h[src[e]] + bias ======
// Block = CT/2 threads, each handles 2 fp16 channels (32-bit gathers).
// Edge indices pre-gathered per wave (one coalesced csr load per 64 edges),
// distributed via __shfl; row gathers issued in independent groups of 8 (ILP).
// att loads are wave-uniform (head uniform per wave) -> broadcast.
template <int CT, int H, int ACT, int WF, int WH>
__global__ void k_agg(const _Float16* __restrict__ h, const float* __restrict__ att,
                      const int* __restrict__ rowptr, const int* __restrict__ csr,
                      const float* __restrict__ bias, const float* __restrict__ prelu_a,
                      float* __restrict__ outf, _Float16* __restrict__ outh) {
  constexpr int CH = CT / H;
  int node = blockIdx.x;
  int t = threadIdx.x;            // 0 .. CT/2-1
  int c0 = t * 2;
  int head = c0 / CH;             // uniform within a wave (CH >= 128)
  int lane = t & 63;
  int beg = rowptr[node];
  int cnt = rowptr[node + 1] - beg;
  float a0 = 0.f, a1 = 0.f;
  for (int base = 0; base < cnt; base += 64) {
    int rem = cnt - base; if (rem > 64) rem = 64;
    int idx = (lane < rem) ? csr[beg + base + lane] : 0;
    int kk = 0;
    for (; kk + 8 <= rem; kk += 8) {
      int s[8]; float w[8]; uint32_t u[8];
#pragma unroll
      for (int j = 0; j < 8; ++j) s[j] = __shfl(idx, kk + j);
#pragma unroll
      for (int j = 0; j < 8; ++j) w[j] = att[(beg + base + kk + j) * H + head];
#pragma unroll
      for (int j = 0; j < 8; ++j)
        u[j] = *(const uint32_t*)&h[(size_t)s[j] * CT + c0];
#pragma unroll
      for (int j = 0; j < 8; ++j) {
        H2 p; p.u = u[j];
        a0 += w[j] * (float)p.f[0];
        a1 += w[j] * (float)p.f[1];
      }
    }
    // tail (up to 7), still grouped for ILP
    {
      int rem2 = rem - kk;
      int s[7]; float w[7]; uint32_t u[7];
#pragma unroll
      for (int j = 0; j < 7; ++j) {
        if (j < rem2) {
          s[j] = __shfl(idx, kk + j);
          w[j] = att[(beg + base + kk + j) * H + head];
        }
      }
#pragma unroll
      for (int j = 0; j < 7; ++j)
        if (j < rem2) u[j] = *(const uint32_t*)&h[(size_t)s[j] * CT + c0];
#pragma unroll
      for (int j = 0; j < 7; ++j) {
        if (j < rem2) {
          H2 p; p.u = u[j];
          a0 += w[j] * (float)p.f[0];
          a1 += w[j] * (float)p.f[1];
        }
      }
    }
  }
  float o0 = a0 + bias[c0];
  float o1 = a1 + bias[c0 + 1];
  if (ACT) {
    float a = prelu_a[0];
    o0 = (o0 >= 0.f) ? o0 : a * o0;
    o1 = (o1 >= 0.f) ? o1 : a * o1;
  }
  if (WF) {
    float2 o = make_float2(o0, o1);
    *(float2*)&outf[(size_t)node * CT + c0] = o;
  }
  if (WH) {
    H2 p; p.f[0] = (_Float16)o0; p.f[1] = (_Float16)o1;
    *(uint32_t*)&outh[(size_t)node * CT + c0] = p.u;
  }
}

// ================= launch =================
extern "C" void kernel_launch(void* const* d_in, const int* in_sizes, int n_in,
                              void* d_out, int out_size, void* d_ws, size_t ws_size,
                              hipStream_t stream) {
  const float* x      = (const float*)d_in[0];
  const int*   ei     = (const int*)d_in[1];
  const float* W1     = (const float*)d_in[2];
  const float* a_s1   = (const float*)d_in[3];
  const float* a_d1   = (const float*)d_in[4];
  const float* b1     = (const float*)d_in[5];
  const float* prelu  = (const float*)d_in[6];
  const float* W2     = (const float*)d_in[7];
  const float* a_s2   = (const float*)d_in[8];
  const float* a_d2   = (const float*)d_in[9];
  const float* b2     = (const float*)d_in[10];
  const float* Wd     = (const float*)d_in[11];
  const float* a_sd   = (const float*)d_in[12];
  const float* a_dd   = (const float*)d_in[13];
  const float* bd     = (const float*)d_in[14];

  const int N = in_sizes[0] / 256;   // 50000
  const int E = in_sizes[1] / 2;     // 400000
  const int* e_src = ei;
  const int* e_dst = ei + E;

  float* z    = (float*)d_out;           // N*256 fp32
  float* xhat = z + (size_t)N * 256;     // N*256 fp32

  // out1_h (layer-1 fp16 output, N*512 f16) lives in the xhat half of d_out:
  // dead after the layer-2 GEMM; xhat written only by the decoder's final agg.
  _Float16* out1_h = (_Float16*)xhat;

  // ---- workspace (~62 MB) ----
  char* wp = (char*)d_ws;
  auto alloc = [&](size_t bytes) { char* p = wp; wp += (bytes + 15) & ~(size_t)15; return p; };
  _Float16* h_h  = (_Float16*)alloc((size_t)N * 512 * 2);  // h1 / h2 / h3
  float* alpS    = (float*)alloc((size_t)N * 4 * 4);
  float* alpD    = (float*)alloc((size_t)N * 4 * 4);
  float* att     = (float*)alloc((size_t)(E + N) * 4 * 4);
  int* rowptr    = (int*)alloc((size_t)(N + 1) * 4);
  int* csr       = (int*)alloc((size_t)(E + N) * 4);
  int* cursor    = (int*)alloc((size_t)N * 4);
  int* counts    = (int*)alloc((size_t)N * 4);
  _Float16* Wt1  = (_Float16*)alloc((size_t)512 * 256 * 2);
  _Float16* Wt2  = (_Float16*)alloc((size_t)256 * 512 * 2);
  _Float16* Wtd  = (_Float16*)alloc((size_t)256 * 256 * 2);

  const int B = 256;
  const int gN = (N + B - 1) / B;
  const int gE = (E + B - 1) / B;

  // ---- CSR (built once, reused for all 3 layers) ----
  k_init_counts<<<gN, B, 0, stream>>>(counts, N);
  k_hist<<<gE, B, 0, stream>>>(e_dst, counts, E);
  k_scan<<<1, B, 0, stream>>>(counts, rowptr, N);
  k_init_csr<<<gN, B, 0, stream>>>(rowptr, cursor, csr, N);
  k_fill<<<gE, B, 0, stream>>>(e_src, e_dst, cursor, csr, E);

  // ---- weight converts (fp32 KxN -> fp16 NxK) ----
  k_w2h<<<(256 * 512 + B - 1) / B, B, 0, stream>>>(W1, Wt1, 256, 512);
  k_w2h<<<(512 * 256 + B - 1) / B, B, 0, stream>>>(W2, Wt2, 512, 256);
  k_w2h<<<(256 * 256 + B - 1) / B, B, 0, stream>>>(Wd, Wtd, 256, 256);

  const int gy = (N + 127) / 128;

  // ---- layer 1: 256 -> 4x128 concat, PReLU ----
  {
    dim3 grid(512 / 64, gy);
    k_gemm_f16<true><<<grid, B, 0, stream>>>(x, Wt1, h_h, N, 512, 256);
    int tot = N * 4;
    k_alpha<4, 128><<<(tot * 64 + B - 1) / B, B, 0, stream>>>(h_h, a_s1, a_d1, alpS, alpD, tot);
    k_att<4><<<(tot + B - 1) / B, B, 0, stream>>>(alpS, alpD, rowptr, csr, att, N);
    k_agg<512, 4, 1, 0, 1><<<N, 256, 0, stream>>>(h_h, att, rowptr, csr, b1, prelu, nullptr, out1_h);
  }

  // ---- layer 2: 512 -> 256, 1 head; writes z (fp32 in d_out) ----
  {
    dim3 grid(256 / 64, gy);
    k_gemm_f16<false><<<grid, B, 0, stream>>>(out1_h, Wt2, h_h, N, 256, 512);
    k_alpha<1, 256><<<(N * 64 + B - 1) / B, B, 0, stream>>>(h_h, a_s2, a_d2, alpS, alpD, N);
    k_att<1><<<gN, B, 0, stream>>>(alpS, alpD, rowptr, csr, att, N);
    k_agg<256, 1, 0, 1, 0><<<N, 128, 0, stream>>>(h_h, att, rowptr, csr, b2, prelu, z, nullptr);
  }

  // ---- decoder: 256 -> 256, 1 head; reads z (fp32), writes xhat ----
  {
    dim3 grid(256 / 64, gy);
    k_gemm_f16<true><<<grid, B, 0, stream>>>(z, Wtd, h_h, N, 256, 256);
    k_alpha<1, 256><<<(N * 64 + B - 1) / B, B, 0, stream>>>(h_h, a_sd, a_dd, alpS, alpD, N);
    k_att<1><<<gN, B, 0, stream>>>(alpS, alpD, rowptr, csr, att, N);
    k_agg<256, 1, 0, 1, 0><<<N, 128, 0, stream>>>(h_h, att, rowptr, csr, bd, prelu, xhat, nullptr);
  }
}

// Round 11
// 649.849 us; speedup vs baseline: 2.1727x; 1.1542x over previous
//
#include <hip/hip_runtime.h>
#include <hip/hip_bf16.h>
#include <cstdint>

#define NEG_SLOPE 0.2f

typedef _Float16 f16x8 __attribute__((ext_vector_type(8)));
typedef float f32x4 __attribute__((ext_vector_type(4)));

union H2 { uint32_t u; _Float16 f[2]; };
union H4 { uint2 u2; _Float16 f[4]; };

// ================= CSR build =================
__global__ void k_init_counts(int* __restrict__ counts, int n) {
  int i = blockIdx.x * blockDim.x + threadIdx.x;
  if (i < n) counts[i] = 1;  // self loop
}

__global__ void k_hist(const int* __restrict__ dst, int* __restrict__ counts, int e) {
  int i = blockIdx.x * blockDim.x + threadIdx.x;
  if (i < e) atomicAdd(&counts[dst[i]], 1);
}

// hierarchical scan: block-local inclusive scan + block sums
__global__ void k_scan1(const int* __restrict__ counts, int* __restrict__ pref,
                        int* __restrict__ bsum, int n) {
  __shared__ int sh[256];
  int tid = threadIdx.x;
  int i = blockIdx.x * 256 + tid;
  int v = (i < n) ? counts[i] : 0;
  sh[tid] = v;
  __syncthreads();
  for (int off = 1; off < 256; off <<= 1) {
    int t = (tid >= off) ? sh[tid - off] : 0;
    __syncthreads();
    sh[tid] += t;
    __syncthreads();
  }
  if (i < n) pref[i] = sh[tid];
  if (tid == 255) bsum[blockIdx.x] = sh[255];
}

__global__ void k_scan2(int* __restrict__ bsum, int nb) {  // 1 block, nb<=256
  __shared__ int sh[256];
  int tid = threadIdx.x;
  int v = (tid < nb) ? bsum[tid] : 0;
  sh[tid] = v;
  __syncthreads();
  for (int off = 1; off < 256; off <<= 1) {
    int t = (tid >= off) ? sh[tid - off] : 0;
    __syncthreads();
    sh[tid] += t;
    __syncthreads();
  }
  if (tid < nb) bsum[tid] = sh[tid];
}

__global__ void k_scan3(const int* __restrict__ pref, const int* __restrict__ bsum,
                        int* __restrict__ rowptr, int n) {
  int i = blockIdx.x * blockDim.x + threadIdx.x;
  if (i < n) rowptr[i + 1] = pref[i] + (blockIdx.x ? bsum[blockIdx.x - 1] : 0);
  if (i == 0) rowptr[0] = 0;
}

__global__ void k_init_csr(const int* __restrict__ rowptr, int* __restrict__ cursor,
                           int* __restrict__ csr_src, int n) {
  int i = blockIdx.x * blockDim.x + threadIdx.x;
  if (i < n) { int r = rowptr[i]; csr_src[r] = i; cursor[i] = r + 1; }
}

__global__ void k_fill(const int* __restrict__ src, const int* __restrict__ dst,
                       int* __restrict__ cursor, int* __restrict__ csr_src, int e) {
  int i = blockIdx.x * blockDim.x + threadIdx.x;
  if (i < e) { int p = atomicAdd(&cursor[dst[i]], 1); csr_src[p] = src[i]; }
}

// ================= weight convert: W (KxN fp32) -> Wt (NxK fp16) =================
__global__ void k_w2h(const float* __restrict__ W, _Float16* __restrict__ Wt, int K, int N) {
  int i = blockIdx.x * blockDim.x + threadIdx.x;
  if (i < K * N) {
    int k = i / N, n = i - k * N;
    Wt[(size_t)n * K + k] = (_Float16)W[i];
  }
}

// ================= fp16 MFMA GEMM: C(f16) = A(MxK) @ Bt^T (Bt is NxK) ==========
template <bool A_F32>
__global__ __launch_bounds__(256) void k_gemm_f16(
    const void* __restrict__ Av, const _Float16* __restrict__ Bt,
    _Float16* __restrict__ C, int M, int N, int K) {
  __shared__ _Float16 As[128 * 72];
  __shared__ _Float16 Bs[64 * 72];
  const int tid  = threadIdx.x;
  const int lane = tid & 63;
  const int wid  = tid >> 6;
  const int wm = wid >> 1, wn = wid & 1;
  const int row0 = blockIdx.y * 128, col0 = blockIdx.x * 64;
  const int l15 = lane & 15, l16 = lane >> 4;
  const int srow = tid >> 3;
  const int skc  = (tid & 7) * 8;

  f32x4 acc[4][2] = {};

  for (int k0 = 0; k0 < K; k0 += 64) {
#pragma unroll
    for (int p = 0; p < 4; ++p) {
      int r = p * 32 + srow;
      int gr = row0 + r; if (gr > M - 1) gr = M - 1;
      _Float16 tmp[8];
      if constexpr (A_F32) {
        const float* src = (const float*)Av + (size_t)gr * K + k0 + skc;
        float4 v0 = ((const float4*)src)[0];
        float4 v1 = ((const float4*)src)[1];
        tmp[0] = (_Float16)v0.x; tmp[1] = (_Float16)v0.y;
        tmp[2] = (_Float16)v0.z; tmp[3] = (_Float16)v0.w;
        tmp[4] = (_Float16)v1.x; tmp[5] = (_Float16)v1.y;
        tmp[6] = (_Float16)v1.z; tmp[7] = (_Float16)v1.w;
      } else {
        const _Float16* src = (const _Float16*)Av + (size_t)gr * K + k0 + skc;
        *(uint4*)tmp = *(const uint4*)src;
      }
      *(uint4*)&As[r * 72 + skc] = *(uint4*)tmp;
    }
#pragma unroll
    for (int p = 0; p < 2; ++p) {
      int n = p * 32 + srow;
      const _Float16* src = Bt + (size_t)(col0 + n) * K + k0 + skc;
      *(uint4*)&Bs[n * 72 + skc] = *(const uint4*)src;
    }
    __syncthreads();
#pragma unroll
    for (int ks = 0; ks < 2; ++ks) {
      f16x8 bfrag[2];
#pragma unroll
      for (int nr = 0; nr < 2; ++nr)
        bfrag[nr] = *(const f16x8*)&Bs[(wn * 32 + nr * 16 + l15) * 72 + ks * 32 + l16 * 8];
#pragma unroll
      for (int mr = 0; mr < 4; ++mr) {
        f16x8 afrag = *(const f16x8*)&As[(wm * 64 + mr * 16 + l15) * 72 + ks * 32 + l16 * 8];
#pragma unroll
        for (int nr = 0; nr < 2; ++nr)
          acc[mr][nr] = __builtin_amdgcn_mfma_f32_16x16x32_f16(afrag, bfrag[nr], acc[mr][nr], 0, 0, 0);
      }
    }
    __syncthreads();
  }
#pragma unroll
  for (int mr = 0; mr < 4; ++mr) {
#pragma unroll
    for (int j = 0; j < 4; ++j) {
      int rg = row0 + wm * 64 + mr * 16 + l16 * 4 + j;
      if (rg < M) {
#pragma unroll
        for (int nr = 0; nr < 2; ++nr) {
          int cg = col0 + wn * 32 + nr * 16 + l15;
          C[(size_t)rg * N + cg] = (_Float16)acc[mr][nr][j];
        }
      }
    }
  }
}

// ================= alpha: per (node, head) wave dot over fp16 h =================
template <int H, int CH>
__global__ void k_alpha(const _Float16* __restrict__ h, const float* __restrict__ a_src,
                        const float* __restrict__ a_dst, float* __restrict__ as,
                        float* __restrict__ ad, int total) {
  int wid = (blockIdx.x * blockDim.x + threadIdx.x) >> 6;
  int lane = threadIdx.x & 63;
  if (wid >= total) return;
  int head = wid % H;
  const _Float16* hp = h + (size_t)wid * CH;
  float s1 = 0.f, s2 = 0.f;
  for (int c = lane; c < CH; c += 64) {
    float v = (float)hp[c];
    s1 += v * a_src[head * CH + c];
    s2 += v * a_dst[head * CH + c];
  }
#pragma unroll
  for (int off = 32; off; off >>= 1) {
    s1 += __shfl_down(s1, off);
    s2 += __shfl_down(s2, off);
  }
  if (lane == 0) { as[wid] = s1; ad[wid] = s2; }
}

// ================= fused softmax + aggregation =================
// Per node: each thread owns 4 channels. Wave-parallel softmax: lane l gathers
// edge l's score; shfl_xor reduce within the EC-lane group serving one head;
// weights shfl-broadcast in the FMA pass.
// CT=512,H=4: 2 waves/node, 2 heads/wave, EC=32. CT=256,H=1: 1 wave/node, EC=64.
template <int W>
__device__ __forceinline__ float grp_max(float v) {
#pragma unroll
  for (int o = W / 2; o; o >>= 1) v = fmaxf(v, __shfl_xor(v, o));
  return v;
}
template <int W>
__device__ __forceinline__ float grp_sum(float v) {
#pragma unroll
  for (int o = W / 2; o; o >>= 1) v += __shfl_xor(v, o);
  return v;
}

template <int CT, int H, int ACT, int WF, int WH, int NPB>
__global__ __launch_bounds__(256) void k_agg(
    const _Float16* __restrict__ h, const float* __restrict__ as,
    const float* __restrict__ ad, const int* __restrict__ rowptr,
    const int* __restrict__ csr, const float* __restrict__ bias,
    const float* __restrict__ prelu_a, float* __restrict__ outf,
    _Float16* __restrict__ outh, int n) {
  constexpr int CH  = CT / H;
  constexpr int TPN = CT / 4;                 // threads per node
  constexpr int HPW = (TPN >= 64) ? (64 / (CH / 4)) : 1;  // heads per wave
  constexpr int EC  = 64 / HPW;               // edge-chunk size (lanes per head group)

  int t = threadIdx.x;
  int node = blockIdx.x * NPB + t / TPN;
  if (node >= n) return;
  int nt = t % TPN;                  // thread within node
  int c0 = nt * 4;
  int head = c0 / CH;
  int lane = t & 63;
  int grp = (EC == 64) ? 0 : (lane >> 5);   // head-group within wave
  int gl = lane & (EC - 1);                 // lane within group
  int srcbase = grp * EC;

  int beg = rowptr[node];
  int cnt = rowptr[node + 1] - beg;
  float adv = ad[node * H + head];

  // pass 1: global max over edges for this head
  float m = -1e30f;
  for (int b = 0; b < cnt; b += EC) {
    int i = b + gl;
    float e = -1e30f;
    if (i < cnt) {
      int s = csr[beg + i];
      float v = as[s * H + head] + adv;
      e = (v >= 0.f) ? v : NEG_SLOPE * v;
    }
    m = fmaxf(m, grp_max<EC>(e));
  }

  // pass 2: weights + gather-FMA, normalize at end
  float denom = 0.f;
  float a0 = 0.f, a1 = 0.f, a2 = 0.f, a3 = 0.f;
  for (int b = 0; b < cnt; b += EC) {
    int i = b + gl;
    float w = 0.f; int s = 0;
    if (i < cnt) {
      s = csr[beg + i];
      float v = as[s * H + head] + adv;
      v = (v >= 0.f) ? v : NEG_SLOPE * v;
      w = __expf(v - m);
    }
    denom += grp_sum<EC>(w);
    int nedge = cnt - b; if (nedge > EC) nedge = EC;
    int kk = 0;
    for (; kk + 8 <= nedge; kk += 8) {
      int sj[8]; float wj[8]; H4 uj[8];
#pragma unroll
      for (int j = 0; j < 8; ++j) {
        sj[j] = __shfl(s, srcbase + kk + j);
        wj[j] = __shfl(w, srcbase + kk + j);
      }
#pragma unroll
      for (int j = 0; j < 8; ++j)
        uj[j].u2 = *(const uint2*)&h[(size_t)sj[j] * CT + c0];
#pragma unroll
      for (int j = 0; j < 8; ++j) {
        a0 += wj[j] * (float)uj[j].f[0];
        a1 += wj[j] * (float)uj[j].f[1];
        a2 += wj[j] * (float)uj[j].f[2];
        a3 += wj[j] * (float)uj[j].f[3];
      }
    }
    {
      int rem = nedge - kk;
      int sj[7]; float wj[7]; H4 uj[7];
#pragma unroll
      for (int j = 0; j < 7; ++j) {
        if (j < rem) {
          sj[j] = __shfl(s, srcbase + kk + j);
          wj[j] = __shfl(w, srcbase + kk + j);
        }
      }
#pragma unroll
      for (int j = 0; j < 7; ++j)
        if (j < rem) uj[j].u2 = *(const uint2*)&h[(size_t)sj[j] * CT + c0];
#pragma unroll
      for (int j = 0; j < 7; ++j) {
        if (j < rem) {
          a0 += wj[j] * (float)uj[j].f[0];
          a1 += wj[j] * (float)uj[j].f[1];
          a2 += wj[j] * (float)uj[j].f[2];
          a3 += wj[j] * (float)uj[j].f[3];
        }
      }
    }
  }

  float inv = 1.f / (denom + 1e-16f);
  float4 bv = *(const float4*)&bias[c0];
  float o0 = a0 * inv + bv.x;
  float o1 = a1 * inv + bv.y;
  float o2 = a2 * inv + bv.z;
  float o3 = a3 * inv + bv.w;
  if (ACT) {
    float a = prelu_a[0];
    o0 = (o0 >= 0.f) ? o0 : a * o0;
    o1 = (o1 >= 0.f) ? o1 : a * o1;
    o2 = (o2 >= 0.f) ? o2 : a * o2;
    o3 = (o3 >= 0.f) ? o3 : a * o3;
  }
  if (WF) {
    float4 o = make_float4(o0, o1, o2, o3);
    *(float4*)&outf[(size_t)node * CT + c0] = o;
  }
  if (WH) {
    H4 p;
    p.f[0] = (_Float16)o0; p.f[1] = (_Float16)o1;
    p.f[2] = (_Float16)o2; p.f[3] = (_Float16)o3;
    *(uint2*)&outh[(size_t)node * CT + c0] = p.u2;
  }
}

// ================= launch =================
extern "C" void kernel_launch(void* const* d_in, const int* in_sizes, int n_in,
                              void* d_out, int out_size, void* d_ws, size_t ws_size,
                              hipStream_t stream) {
  const float* x      = (const float*)d_in[0];
  const int*   ei     = (const int*)d_in[1];
  const float* W1     = (const float*)d_in[2];
  const float* a_s1   = (const float*)d_in[3];
  const float* a_d1   = (const float*)d_in[4];
  const float* b1     = (const float*)d_in[5];
  const float* prelu  = (const float*)d_in[6];
  const float* W2     = (const float*)d_in[7];
  const float* a_s2   = (const float*)d_in[8];
  const float* a_d2   = (const float*)d_in[9];
  const float* b2     = (const float*)d_in[10];
  const float* Wd     = (const float*)d_in[11];
  const float* a_sd   = (const float*)d_in[12];
  const float* a_dd   = (const float*)d_in[13];
  const float* bd     = (const float*)d_in[14];

  const int N = in_sizes[0] / 256;   // 50000
  const int E = in_sizes[1] / 2;     // 400000
  const int* e_src = ei;
  const int* e_dst = ei + E;

  float* z    = (float*)d_out;           // N*256 fp32
  float* xhat = z + (size_t)N * 256;     // N*256 fp32

  // out1_h (layer-1 fp16 output, N*512 f16) lives in the xhat half of d_out:
  // dead after the layer-2 GEMM; xhat written only by the decoder's final agg.
  _Float16* out1_h = (_Float16*)xhat;

  // ---- workspace (~56 MB) ----
  char* wp = (char*)d_ws;
  auto alloc = [&](size_t bytes) { char* p = wp; wp += (bytes + 15) & ~(size_t)15; return p; };
  _Float16* h_h  = (_Float16*)alloc((size_t)N * 512 * 2);  // h1 / h2 / h3
  float* alpS    = (float*)alloc((size_t)N * 4 * 4);
  float* alpD    = (float*)alloc((size_t)N * 4 * 4);
  int* rowptr    = (int*)alloc((size_t)(N + 1) * 4);
  int* csr       = (int*)alloc((size_t)(E + N) * 4);
  int* cursor    = (int*)alloc((size_t)N * 4);
  int* counts    = (int*)alloc((size_t)N * 4);
  int* pref      = (int*)alloc((size_t)N * 4);
  int* bsum      = (int*)alloc((size_t)256 * 4);
  _Float16* Wt1  = (_Float16*)alloc((size_t)512 * 256 * 2);
  _Float16* Wt2  = (_Float16*)alloc((size_t)256 * 512 * 2);
  _Float16* Wtd  = (_Float16*)alloc((size_t)256 * 256 * 2);

  const int B = 256;
  const int gN = (N + B - 1) / B;
  const int gE = (E + B - 1) / B;

  // ---- CSR (built once, reused for all 3 layers) ----
  k_init_counts<<<gN, B, 0, stream>>>(counts, N);
  k_hist<<<gE, B, 0, stream>>>(e_dst, counts, E);
  k_scan1<<<gN, B, 0, stream>>>(counts, pref, bsum, N);
  k_scan2<<<1, B, 0, stream>>>(bsum, gN);
  k_scan3<<<gN, B, 0, stream>>>(pref, bsum, rowptr, N);
  k_init_csr<<<gN, B, 0, stream>>>(rowptr, cursor, csr, N);
  k_fill<<<gE, B, 0, stream>>>(e_src, e_dst, cursor, csr, E);

  // ---- weight converts (fp32 KxN -> fp16 NxK) ----
  k_w2h<<<(256 * 512 + B - 1) / B, B, 0, stream>>>(W1, Wt1, 256, 512);
  k_w2h<<<(512 * 256 + B - 1) / B, B, 0, stream>>>(W2, Wt2, 512, 256);
  k_w2h<<<(256 * 256 + B - 1) / B, B, 0, stream>>>(Wd, Wtd, 256, 256);

  const int gy = (N + 127) / 128;

  // ---- layer 1: 256 -> 4x128 concat, PReLU ----
  {
    dim3 grid(512 / 64, gy);
    k_gemm_f16<true><<<grid, B, 0, stream>>>(x, Wt1, h_h, N, 512, 256);
    int tot = N * 4;
    k_alpha<4, 128><<<(tot * 64 + B - 1) / B, B, 0, stream>>>(h_h, a_s1, a_d1, alpS, alpD, tot);
    k_agg<512, 4, 1, 0, 1, 2><<<(N + 1) / 2, B, 0, stream>>>(
        h_h, alpS, alpD, rowptr, csr, b1, prelu, nullptr, out1_h, N);
  }

  // ---- layer 2: 512 -> 256, 1 head; writes z (fp32 in d_out) ----
  {
    dim3 grid(256 / 64, gy);
    k_gemm_f16<false><<<grid, B, 0, stream>>>(out1_h, Wt2, h_h, N, 256, 512);
    k_alpha<1, 256><<<(N * 64 + B - 1) / B, B, 0, stream>>>(h_h, a_s2, a_d2, alpS, alpD, N);
    k_agg<256, 1, 0, 1, 0, 4><<<(N + 3) / 4, B, 0, stream>>>(
        h_h, alpS, alpD, rowptr, csr, b2, prelu, z, nullptr, N);
  }

  // ---- decoder: 256 -> 256, 1 head; reads z (fp32), writes xhat ----
  {
    dim3 grid(256 / 64, gy);
    k_gemm_f16<true><<<grid, B, 0, stream>>>(z, Wtd, h_h, N, 256, 256);
    k_alpha<1, 256><<<(N * 64 + B - 1) / B, B, 0, stream>>>(h_h, a_sd, a_dd, alpS, alpD, N);
    k_agg<256, 1, 0, 1, 0, 4><<<(N + 3) / 4, B, 0, stream>>>(
        h_h, alpS, alpD, rowptr, csr, bd, prelu, xhat, nullptr, N);
  }
}

// Round 12
// 591.002 us; speedup vs baseline: 2.3891x; 1.0996x over previous
//
#include <hip/hip_runtime.h>
#include <hip/hip_bf16.h>
#include <cstdint>

#define NEG_SLOPE 0.2f

typedef _Float16 f16x8 __attribute__((ext_vector_type(8)));
typedef float f32x4 __attribute__((ext_vector_type(4)));

union H2 { uint32_t u; _Float16 f[2]; };
union H4 { uint2 u2; _Float16 f[4]; };

// ================= CSR build =================
__global__ void k_init_counts(int* __restrict__ counts, int n) {
  int i = blockIdx.x * blockDim.x + threadIdx.x;
  if (i < n) counts[i] = 1;  // self loop
}

__global__ void k_hist(const int* __restrict__ dst, int* __restrict__ counts, int e) {
  int i = blockIdx.x * blockDim.x + threadIdx.x;
  if (i < e) atomicAdd(&counts[dst[i]], 1);
}

// hierarchical scan
__global__ void k_scan1(const int* __restrict__ counts, int* __restrict__ pref,
                        int* __restrict__ bsum, int n) {
  __shared__ int sh[256];
  int tid = threadIdx.x;
  int i = blockIdx.x * 256 + tid;
  int v = (i < n) ? counts[i] : 0;
  sh[tid] = v;
  __syncthreads();
  for (int off = 1; off < 256; off <<= 1) {
    int t = (tid >= off) ? sh[tid - off] : 0;
    __syncthreads();
    sh[tid] += t;
    __syncthreads();
  }
  if (i < n) pref[i] = sh[tid];
  if (tid == 255) bsum[blockIdx.x] = sh[255];
}

__global__ void k_scan2(int* __restrict__ bsum, int nb) {
  __shared__ int sh[256];
  int tid = threadIdx.x;
  int v = (tid < nb) ? bsum[tid] : 0;
  sh[tid] = v;
  __syncthreads();
  for (int off = 1; off < 256; off <<= 1) {
    int t = (tid >= off) ? sh[tid - off] : 0;
    __syncthreads();
    sh[tid] += t;
    __syncthreads();
  }
  if (tid < nb) bsum[tid] = sh[tid];
}

__global__ void k_scan3(const int* __restrict__ pref, const int* __restrict__ bsum,
                        int* __restrict__ rowptr, int n) {
  int i = blockIdx.x * blockDim.x + threadIdx.x;
  if (i < n) rowptr[i + 1] = pref[i] + (blockIdx.x ? bsum[blockIdx.x - 1] : 0);
  if (i == 0) rowptr[0] = 0;
}

__global__ void k_init_csr(const int* __restrict__ rowptr, int* __restrict__ cursor,
                           int* __restrict__ csr_src, int n) {
  int i = blockIdx.x * blockDim.x + threadIdx.x;
  if (i < n) { int r = rowptr[i]; csr_src[r] = i; cursor[i] = r + 1; }
}

__global__ void k_fill(const int* __restrict__ src, const int* __restrict__ dst,
                       int* __restrict__ cursor, int* __restrict__ csr_src, int e) {
  int i = blockIdx.x * blockDim.x + threadIdx.x;
  if (i < e) { int p = atomicAdd(&cursor[dst[i]], 1); csr_src[p] = src[i]; }
}

// ================= weight convert: W (KxN fp32) -> Wt (NxK fp16) =================
__global__ void k_w2h(const float* __restrict__ W, _Float16* __restrict__ Wt, int K, int N) {
  int i = blockIdx.x * blockDim.x + threadIdx.x;
  if (i < K * N) {
    int k = i / N, n = i - k * N;
    Wt[(size_t)n * K + k] = (_Float16)W[i];
  }
}

// ================= fp16 MFMA GEMM: C(f16) = A(MxK) @ Bt^T (Bt is NxK) ==========
// BM=256, BN=128, BK=64. 512 threads = 8 waves (4m x 2n); per-wave out 64x64.
// N must be a multiple of 128; K multiple of 64.
template <bool A_F32>
__global__ __launch_bounds__(512) void k_gemm_f16(
    const void* __restrict__ Av, const _Float16* __restrict__ Bt,
    _Float16* __restrict__ C, int M, int N, int K) {
  __shared__ _Float16 As[256 * 72];
  __shared__ _Float16 Bs[128 * 72];
  const int tid  = threadIdx.x;       // 0..511
  const int lane = tid & 63;
  const int wid  = tid >> 6;          // 0..7
  const int wm = wid >> 1;            // 0..3
  const int wn = wid & 1;             // 0..1
  const int row0 = blockIdx.y * 256, col0 = blockIdx.x * 128;
  const int l15 = lane & 15, l16 = lane >> 4;
  const int srow = tid >> 3;          // 0..63
  const int skc  = (tid & 7) * 8;     // f16 offset 0..56

  f32x4 acc[4][4] = {};

  for (int k0 = 0; k0 < K; k0 += 64) {
    // stage A: 256 rows x 64 k
#pragma unroll
    for (int p = 0; p < 4; ++p) {
      int r = p * 64 + srow;
      int gr = row0 + r; if (gr > M - 1) gr = M - 1;
      _Float16 tmp[8];
      if constexpr (A_F32) {
        const float* src = (const float*)Av + (size_t)gr * K + k0 + skc;
        float4 v0 = ((const float4*)src)[0];
        float4 v1 = ((const float4*)src)[1];
        tmp[0] = (_Float16)v0.x; tmp[1] = (_Float16)v0.y;
        tmp[2] = (_Float16)v0.z; tmp[3] = (_Float16)v0.w;
        tmp[4] = (_Float16)v1.x; tmp[5] = (_Float16)v1.y;
        tmp[6] = (_Float16)v1.z; tmp[7] = (_Float16)v1.w;
      } else {
        const _Float16* src = (const _Float16*)Av + (size_t)gr * K + k0 + skc;
        *(uint4*)tmp = *(const uint4*)src;
      }
      *(uint4*)&As[r * 72 + skc] = *(uint4*)tmp;
    }
    // stage B: 128 out-cols x 64 k
#pragma unroll
    for (int p = 0; p < 2; ++p) {
      int nr_ = p * 64 + srow;
      const _Float16* src = Bt + (size_t)(col0 + nr_) * K + k0 + skc;
      *(uint4*)&Bs[nr_ * 72 + skc] = *(const uint4*)src;
    }
    __syncthreads();
#pragma unroll
    for (int ks = 0; ks < 2; ++ks) {
      f16x8 bfrag[4];
#pragma unroll
      for (int nr = 0; nr < 4; ++nr)
        bfrag[nr] = *(const f16x8*)&Bs[(wn * 64 + nr * 16 + l15) * 72 + ks * 32 + l16 * 8];
#pragma unroll
      for (int mr = 0; mr < 4; ++mr) {
        f16x8 afrag = *(const f16x8*)&As[(wm * 64 + mr * 16 + l15) * 72 + ks * 32 + l16 * 8];
#pragma unroll
        for (int nr = 0; nr < 4; ++nr)
          acc[mr][nr] = __builtin_amdgcn_mfma_f32_16x16x32_f16(afrag, bfrag[nr], acc[mr][nr], 0, 0, 0);
      }
    }
    __syncthreads();
  }
  // epilogue: C/D map col=lane&15, row=(lane>>4)*4+reg
#pragma unroll
  for (int mr = 0; mr < 4; ++mr) {
#pragma unroll
    for (int j = 0; j < 4; ++j) {
      int rg = row0 + wm * 64 + mr * 16 + l16 * 4 + j;
      if (rg < M) {
#pragma unroll
        for (int nr = 0; nr < 4; ++nr) {
          int cg = col0 + wn * 64 + nr * 16 + l15;
          C[(size_t)rg * N + cg] = (_Float16)acc[mr][nr][j];
        }
      }
    }
  }
}

// ================= alpha: per (node, head) wave dot over fp16 h =================
template <int H, int CH>
__global__ void k_alpha(const _Float16* __restrict__ h, const float* __restrict__ a_src,
                        const float* __restrict__ a_dst, float* __restrict__ as,
                        float* __restrict__ ad, int total) {
  int wid = (blockIdx.x * blockDim.x + threadIdx.x) >> 6;
  int lane = threadIdx.x & 63;
  if (wid >= total) return;
  int head = wid % H;
  const _Float16* hp = h + (size_t)wid * CH;
  const float* asp = a_src + head * CH;
  const float* adp = a_dst + head * CH;
  float s1 = 0.f, s2 = 0.f;
  for (int c = lane * 2; c < CH; c += 128) {
    H2 v; v.u = *(const uint32_t*)&hp[c];
    float v0 = (float)v.f[0], v1 = (float)v.f[1];
    s1 += v0 * asp[c] + v1 * asp[c + 1];
    s2 += v0 * adp[c] + v1 * adp[c + 1];
  }
#pragma unroll
  for (int off = 32; off; off >>= 1) {
    s1 += __shfl_down(s1, off);
    s2 += __shfl_down(s2, off);
  }
  if (lane == 0) { as[wid] = s1; ad[wid] = s2; }
}

// ================= fused softmax + aggregation (single pass, no max-sub) ======
// exp(e)/sum(exp(e)) == exp(e-m)/sum(exp(e-m)); scores bounded (|e| ~ <10) so
// raw exp is safe in fp32. One edge walk: gather score -> w=exp -> grp_sum
// denom; shfl-broadcast (s,w); 8B h-gathers, 8-wide ILP; normalize at end.
template <int W>
__device__ __forceinline__ float grp_sum(float v) {
#pragma unroll
  for (int o = W / 2; o; o >>= 1) v += __shfl_xor(v, o);
  return v;
}

template <int CT, int H, int ACT, int WF, int WH, int NPB>
__global__ __launch_bounds__(256) void k_agg(
    const _Float16* __restrict__ h, const float* __restrict__ as,
    const float* __restrict__ ad, const int* __restrict__ rowptr,
    const int* __restrict__ csr, const float* __restrict__ bias,
    const float* __restrict__ prelu_a, float* __restrict__ outf,
    _Float16* __restrict__ outh, int n) {
  constexpr int CH  = CT / H;
  constexpr int TPN = CT / 4;                 // threads per node
  constexpr int HPW = (TPN >= 64) ? (64 / (CH / 4)) : 1;  // heads per wave
  constexpr int EC  = 64 / HPW;               // edge-chunk (lanes per head group)

  int t = threadIdx.x;
  int node = blockIdx.x * NPB + t / TPN;
  if (node >= n) return;
  int nt = t % TPN;
  int c0 = nt * 4;
  int head = c0 / CH;
  int lane = t & 63;
  int grp = (EC == 64) ? 0 : (lane >> 5);
  int gl = lane & (EC - 1);
  int srcbase = grp * EC;

  int beg = rowptr[node];
  int cnt = rowptr[node + 1] - beg;
  float adv = ad[node * H + head];

  float denom = 0.f;
  float a0 = 0.f, a1 = 0.f, a2 = 0.f, a3 = 0.f;
  for (int b = 0; b < cnt; b += EC) {
    int i = b + gl;
    float w = 0.f; int s = 0;
    if (i < cnt) {
      s = csr[beg + i];
      float v = as[s * H + head] + adv;
      v = (v >= 0.f) ? v : NEG_SLOPE * v;
      w = __expf(v);
    }
    denom += grp_sum<EC>(w);
    int nedge = cnt - b; if (nedge > EC) nedge = EC;
    int kk = 0;
    for (; kk + 8 <= nedge; kk += 8) {
      int sj[8]; float wj[8]; H4 uj[8];
#pragma unroll
      for (int j = 0; j < 8; ++j) {
        sj[j] = __shfl(s, srcbase + kk + j);
        wj[j] = __shfl(w, srcbase + kk + j);
      }
#pragma unroll
      for (int j = 0; j < 8; ++j)
        uj[j].u2 = *(const uint2*)&h[(size_t)sj[j] * CT + c0];
#pragma unroll
      for (int j = 0; j < 8; ++j) {
        a0 += wj[j] * (float)uj[j].f[0];
        a1 += wj[j] * (float)uj[j].f[1];
        a2 += wj[j] * (float)uj[j].f[2];
        a3 += wj[j] * (float)uj[j].f[3];
      }
    }
    {
      int rem = nedge - kk;
      int sj[7]; float wj[7]; H4 uj[7];
#pragma unroll
      for (int j = 0; j < 7; ++j) {
        if (j < rem) {
          sj[j] = __shfl(s, srcbase + kk + j);
          wj[j] = __shfl(w, srcbase + kk + j);
        }
      }
#pragma unroll
      for (int j = 0; j < 7; ++j)
        if (j < rem) uj[j].u2 = *(const uint2*)&h[(size_t)sj[j] * CT + c0];
#pragma unroll
      for (int j = 0; j < 7; ++j) {
        if (j < rem) {
          a0 += wj[j] * (float)uj[j].f[0];
          a1 += wj[j] * (float)uj[j].f[1];
          a2 += wj[j] * (float)uj[j].f[2];
          a3 += wj[j] * (float)uj[j].f[3];
        }
      }
    }
  }

  float inv = 1.f / (denom + 1e-16f);
  float4 bv = *(const float4*)&bias[c0];
  float o0 = a0 * inv + bv.x;
  float o1 = a1 * inv + bv.y;
  float o2 = a2 * inv + bv.z;
  float o3 = a3 * inv + bv.w;
  if (ACT) {
    float a = prelu_a[0];
    o0 = (o0 >= 0.f) ? o0 : a * o0;
    o1 = (o1 >= 0.f) ? o1 : a * o1;
    o2 = (o2 >= 0.f) ? o2 : a * o2;
    o3 = (o3 >= 0.f) ? o3 : a * o3;
  }
  if (WF) {
    float4 o = make_float4(o0, o1, o2, o3);
    *(float4*)&outf[(size_t)node * CT + c0] = o;
  }
  if (WH) {
    H4 p;
    p.f[0] = (_Float16)o0; p.f[1] = (_Float16)o1;
    p.f[2] = (_Float16)o2; p.f[3] = (_Float16)o3;
    *(uint2*)&outh[(size_t)node * CT + c0] = p.u2;
  }
}

// ================= launch =================
extern "C" void kernel_launch(void* const* d_in, const int* in_sizes, int n_in,
                              void* d_out, int out_size, void* d_ws, size_t ws_size,
                              hipStream_t stream) {
  const float* x      = (const float*)d_in[0];
  const int*   ei     = (const int*)d_in[1];
  const float* W1     = (const float*)d_in[2];
  const float* a_s1   = (const float*)d_in[3];
  const float* a_d1   = (const float*)d_in[4];
  const float* b1     = (const float*)d_in[5];
  const float* prelu  = (const float*)d_in[6];
  const float* W2     = (const float*)d_in[7];
  const float* a_s2   = (const float*)d_in[8];
  const float* a_d2   = (const float*)d_in[9];
  const float* b2     = (const float*)d_in[10];
  const float* Wd     = (const float*)d_in[11];
  const float* a_sd   = (const float*)d_in[12];
  const float* a_dd   = (const float*)d_in[13];
  const float* bd     = (const float*)d_in[14];

  const int N = in_sizes[0] / 256;   // 50000
  const int E = in_sizes[1] / 2;     // 400000
  const int* e_src = ei;
  const int* e_dst = ei + E;

  float* z    = (float*)d_out;           // N*256 fp32
  float* xhat = z + (size_t)N * 256;     // N*256 fp32

  // out1_h (layer-1 fp16 output, N*512 f16) lives in the xhat half of d_out:
  // dead after the layer-2 GEMM; xhat written only by the decoder's final agg.
  _Float16* out1_h = (_Float16*)xhat;

  // ---- workspace (~56 MB) ----
  char* wp = (char*)d_ws;
  auto alloc = [&](size_t bytes) { char* p = wp; wp += (bytes + 15) & ~(size_t)15; return p; };
  _Float16* h_h  = (_Float16*)alloc((size_t)N * 512 * 2);  // h1 / h2 / h3
  float* alpS    = (float*)alloc((size_t)N * 4 * 4);
  float* alpD    = (float*)alloc((size_t)N * 4 * 4);
  int* rowptr    = (int*)alloc((size_t)(N + 1) * 4);
  int* csr       = (int*)alloc((size_t)(E + N) * 4);
  int* cursor    = (int*)alloc((size_t)N * 4);
  int* counts    = (int*)alloc((size_t)N * 4);
  int* pref      = (int*)alloc((size_t)N * 4);
  int* bsum      = (int*)alloc((size_t)256 * 4);
  _Float16* Wt1  = (_Float16*)alloc((size_t)512 * 256 * 2);
  _Float16* Wt2  = (_Float16*)alloc((size_t)256 * 512 * 2);
  _Float16* Wtd  = (_Float16*)alloc((size_t)256 * 256 * 2);

  const int B = 256;
  const int gN = (N + B - 1) / B;
  const int gE = (E + B - 1) / B;

  // ---- CSR (built once, reused for all 3 layers) ----
  k_init_counts<<<gN, B, 0, stream>>>(counts, N);
  k_hist<<<gE, B, 0, stream>>>(e_dst, counts, E);
  k_scan1<<<gN, B, 0, stream>>>(counts, pref, bsum, N);
  k_scan2<<<1, B, 0, stream>>>(bsum, gN);
  k_scan3<<<gN, B, 0, stream>>>(pref, bsum, rowptr, N);
  k_init_csr<<<gN, B, 0, stream>>>(rowptr, cursor, csr, N);
  k_fill<<<gE, B, 0, stream>>>(e_src, e_dst, cursor, csr, E);

  // ---- weight converts (fp32 KxN -> fp16 NxK) ----
  k_w2h<<<(256 * 512 + B - 1) / B, B, 0, stream>>>(W1, Wt1, 256, 512);
  k_w2h<<<(512 * 256 + B - 1) / B, B, 0, stream>>>(W2, Wt2, 512, 256);
  k_w2h<<<(256 * 256 + B - 1) / B, B, 0, stream>>>(Wd, Wtd, 256, 256);

  const int gy = (N + 255) / 256;

  // ---- layer 1: 256 -> 4x128 concat, PReLU ----
  {
    dim3 grid(512 / 128, gy);
    k_gemm_f16<true><<<grid, 512, 0, stream>>>(x, Wt1, h_h, N, 512, 256);
    int tot = N * 4;
    k_alpha<4, 128><<<(tot * 64 + B - 1) / B, B, 0, stream>>>(h_h, a_s1, a_d1, alpS, alpD, tot);
    k_agg<512, 4, 1, 0, 1, 2><<<(N + 1) / 2, B, 0, stream>>>(
        h_h, alpS, alpD, rowptr, csr, b1, prelu, nullptr, out1_h, N);
  }

  // ---- layer 2: 512 -> 256, 1 head; writes z (fp32 in d_out) ----
  {
    dim3 grid(256 / 128, gy);
    k_gemm_f16<false><<<grid, 512, 0, stream>>>(out1_h, Wt2, h_h, N, 256, 512);
    k_alpha<1, 256><<<(N * 64 + B - 1) / B, B, 0, stream>>>(h_h, a_s2, a_d2, alpS, alpD, N);
    k_agg<256, 1, 0, 1, 0, 4><<<(N + 3) / 4, B, 0, stream>>>(
        h_h, alpS, alpD, rowptr, csr, b2, prelu, z, nullptr, N);
  }

  // ---- decoder: 256 -> 256, 1 head; reads z (fp32), writes xhat ----
  {
    dim3 grid(256 / 128, gy);
    k_gemm_f16<true><<<grid, 512, 0, stream>>>(z, Wtd, h_h, N, 256, 256);
    k_alpha<1, 256><<<(N * 64 + B - 1) / B, B, 0, stream>>>(h_h, a_sd, a_dd, alpS, alpD, N);
    k_agg<256, 1, 0, 1, 0, 4><<<(N + 3) / 4, B, 0, stream>>>(
        h_h, alpS, alpD, rowptr, csr, bd, prelu, xhat, nullptr, N);
  }
}

// Round 13
// 524.890 us; speedup vs baseline: 2.6900x; 1.1260x over previous
//
#include <hip/hip_runtime.h>
#include <hip/hip_bf16.h>
#include <cstdint>

#define NEG_SLOPE 0.2f

typedef _Float16 f16x8 __attribute__((ext_vector_type(8)));
typedef float f32x4 __attribute__((ext_vector_type(4)));

union H2 { uint32_t u; _Float16 f[2]; };
union H8 { uint4 u4; _Float16 f[8]; };

// ================= CSR build =================
__global__ void k_init_counts(int* __restrict__ counts, int n) {
  int i = blockIdx.x * blockDim.x + threadIdx.x;
  if (i < n) counts[i] = 1;  // self loop
}

__global__ void k_hist(const int* __restrict__ dst, int* __restrict__ counts, int e) {
  int i = blockIdx.x * blockDim.x + threadIdx.x;
  if (i < e) atomicAdd(&counts[dst[i]], 1);
}

// hierarchical scan
__global__ void k_scan1(const int* __restrict__ counts, int* __restrict__ pref,
                        int* __restrict__ bsum, int n) {
  __shared__ int sh[256];
  int tid = threadIdx.x;
  int i = blockIdx.x * 256 + tid;
  int v = (i < n) ? counts[i] : 0;
  sh[tid] = v;
  __syncthreads();
  for (int off = 1; off < 256; off <<= 1) {
    int t = (tid >= off) ? sh[tid - off] : 0;
    __syncthreads();
    sh[tid] += t;
    __syncthreads();
  }
  if (i < n) pref[i] = sh[tid];
  if (tid == 255) bsum[blockIdx.x] = sh[255];
}

__global__ void k_scan2(int* __restrict__ bsum, int nb) {
  __shared__ int sh[256];
  int tid = threadIdx.x;
  int v = (tid < nb) ? bsum[tid] : 0;
  sh[tid] = v;
  __syncthreads();
  for (int off = 1; off < 256; off <<= 1) {
    int t = (tid >= off) ? sh[tid - off] : 0;
    __syncthreads();
    sh[tid] += t;
    __syncthreads();
  }
  if (tid < nb) bsum[tid] = sh[tid];
}

__global__ void k_scan3(const int* __restrict__ pref, const int* __restrict__ bsum,
                        int* __restrict__ rowptr, int n) {
  int i = blockIdx.x * blockDim.x + threadIdx.x;
  if (i < n) rowptr[i + 1] = pref[i] + (blockIdx.x ? bsum[blockIdx.x - 1] : 0);
  if (i == 0) rowptr[0] = 0;
}

__global__ void k_init_csr(const int* __restrict__ rowptr, int* __restrict__ cursor,
                           int* __restrict__ csr_src, int n) {
  int i = blockIdx.x * blockDim.x + threadIdx.x;
  if (i < n) { int r = rowptr[i]; csr_src[r] = i; cursor[i] = r + 1; }
}

__global__ void k_fill(const int* __restrict__ src, const int* __restrict__ dst,
                       int* __restrict__ cursor, int* __restrict__ csr_src, int e) {
  int i = blockIdx.x * blockDim.x + threadIdx.x;
  if (i < e) { int p = atomicAdd(&cursor[dst[i]], 1); csr_src[p] = src[i]; }
}

// ================= weight convert: W (KxN fp32) -> Wt (NxK fp16) =================
__global__ void k_w2h(const float* __restrict__ W, _Float16* __restrict__ Wt, int K, int N) {
  int i = blockIdx.x * blockDim.x + threadIdx.x;
  if (i < K * N) {
    int k = i / N, n = i - k * N;
    Wt[(size_t)n * K + k] = (_Float16)W[i];
  }
}

// ================= fp16 MFMA GEMM: C(f16) = A(MxK) @ Bt^T (Bt is NxK) ==========
// BM=256, BN=128, BK=64. 512 threads = 8 waves (4m x 2n); per-wave out 64x64.
template <bool A_F32>
__global__ __launch_bounds__(512) void k_gemm_f16(
    const void* __restrict__ Av, const _Float16* __restrict__ Bt,
    _Float16* __restrict__ C, int M, int N, int K) {
  __shared__ _Float16 As[256 * 72];
  __shared__ _Float16 Bs[128 * 72];
  const int tid  = threadIdx.x;
  const int lane = tid & 63;
  const int wid  = tid >> 6;
  const int wm = wid >> 1;
  const int wn = wid & 1;
  const int row0 = blockIdx.y * 256, col0 = blockIdx.x * 128;
  const int l15 = lane & 15, l16 = lane >> 4;
  const int srow = tid >> 3;
  const int skc  = (tid & 7) * 8;

  f32x4 acc[4][4] = {};

  for (int k0 = 0; k0 < K; k0 += 64) {
#pragma unroll
    for (int p = 0; p < 4; ++p) {
      int r = p * 64 + srow;
      int gr = row0 + r; if (gr > M - 1) gr = M - 1;
      _Float16 tmp[8];
      if constexpr (A_F32) {
        const float* src = (const float*)Av + (size_t)gr * K + k0 + skc;
        float4 v0 = ((const float4*)src)[0];
        float4 v1 = ((const float4*)src)[1];
        tmp[0] = (_Float16)v0.x; tmp[1] = (_Float16)v0.y;
        tmp[2] = (_Float16)v0.z; tmp[3] = (_Float16)v0.w;
        tmp[4] = (_Float16)v1.x; tmp[5] = (_Float16)v1.y;
        tmp[6] = (_Float16)v1.z; tmp[7] = (_Float16)v1.w;
      } else {
        const _Float16* src = (const _Float16*)Av + (size_t)gr * K + k0 + skc;
        *(uint4*)tmp = *(const uint4*)src;
      }
      *(uint4*)&As[r * 72 + skc] = *(uint4*)tmp;
    }
#pragma unroll
    for (int p = 0; p < 2; ++p) {
      int nr_ = p * 64 + srow;
      const _Float16* src = Bt + (size_t)(col0 + nr_) * K + k0 + skc;
      *(uint4*)&Bs[nr_ * 72 + skc] = *(const uint4*)src;
    }
    __syncthreads();
#pragma unroll
    for (int ks = 0; ks < 2; ++ks) {
      f16x8 bfrag[4];
#pragma unroll
      for (int nr = 0; nr < 4; ++nr)
        bfrag[nr] = *(const f16x8*)&Bs[(wn * 64 + nr * 16 + l15) * 72 + ks * 32 + l16 * 8];
#pragma unroll
      for (int mr = 0; mr < 4; ++mr) {
        f16x8 afrag = *(const f16x8*)&As[(wm * 64 + mr * 16 + l15) * 72 + ks * 32 + l16 * 8];
#pragma unroll
        for (int nr = 0; nr < 4; ++nr)
          acc[mr][nr] = __builtin_amdgcn_mfma_f32_16x16x32_f16(afrag, bfrag[nr], acc[mr][nr], 0, 0, 0);
      }
    }
    __syncthreads();
  }
#pragma unroll
  for (int mr = 0; mr < 4; ++mr) {
#pragma unroll
    for (int j = 0; j < 4; ++j) {
      int rg = row0 + wm * 64 + mr * 16 + l16 * 4 + j;
      if (rg < M) {
#pragma unroll
        for (int nr = 0; nr < 4; ++nr) {
          int cg = col0 + wn * 64 + nr * 16 + l15;
          C[(size_t)rg * N + cg] = (_Float16)acc[mr][nr][j];
        }
      }
    }
  }
}

// ================= alpha: per (node, head) wave dot over fp16 h =================
template <int H, int CH>
__global__ void k_alpha(const _Float16* __restrict__ h, const float* __restrict__ a_src,
                        const float* __restrict__ a_dst, float* __restrict__ as,
                        float* __restrict__ ad, int total) {
  int wid = (blockIdx.x * blockDim.x + threadIdx.x) >> 6;
  int lane = threadIdx.x & 63;
  if (wid >= total) return;
  int head = wid % H;
  const _Float16* hp = h + (size_t)wid * CH;
  const float* asp = a_src + head * CH;
  const float* adp = a_dst + head * CH;
  float s1 = 0.f, s2 = 0.f;
  for (int c = lane * 2; c < CH; c += 128) {
    H2 v; v.u = *(const uint32_t*)&hp[c];
    float v0 = (float)v.f[0], v1 = (float)v.f[1];
    s1 += v0 * asp[c] + v1 * asp[c + 1];
    s2 += v0 * adp[c] + v1 * adp[c + 1];
  }
#pragma unroll
  for (int off = 32; off; off >>= 1) {
    s1 += __shfl_down(s1, off);
    s2 += __shfl_down(s2, off);
  }
  if (lane == 0) { as[wid] = s1; ad[wid] = s2; }
}

// ====== fused softmax + aggregation, persistent grid-stride waves ======
// 8 f16 channels/thread (uint4 gathers). TPN=CT/8 threads per node (64 or 32);
// NSW=64/TPN nodes served per wave. G=CH/8 lanes share one (node,head):
// lane gl of the group gathers edge (b+gl)'s score (single pass, no max-sub:
// exp(e)/sum == exp(e-m)/sum(e-m), scores bounded so fp32-safe); shfl
// broadcasts (s,w); 16B h-row gathers with 4-wide ILP. Persistent loop keeps
// all waves resident (occupancy) instead of 25K short blocks.
template <int W>
__device__ __forceinline__ float grp_sum(float v) {
#pragma unroll
  for (int o = W / 2; o; o >>= 1) v += __shfl_xor(v, o);
  return v;
}

template <int CT, int H, int ACT, int WF, int WH>
__global__ __launch_bounds__(256) void k_agg(
    const _Float16* __restrict__ h, const float* __restrict__ as,
    const float* __restrict__ ad, const int* __restrict__ rowptr,
    const int* __restrict__ csr, const float* __restrict__ bias,
    const float* __restrict__ prelu_a, float* __restrict__ outf,
    _Float16* __restrict__ outh, int n) {
  constexpr int CH  = CT / H;
  constexpr int TPN = CT / 8;       // threads per node: 64 (CT=512) / 32 (CT=256)
  constexpr int NSW = 64 / TPN;     // nodes per wave: 1 / 2
  constexpr int G   = CH / 8;       // lanes per (node,head) group: 16 / 32

  int lane = threadIdx.x & 63;
  int wib  = threadIdx.x >> 6;
  int slot0  = (blockIdx.x * (256 >> 6) + wib) * NSW + ((NSW == 2) ? (lane >> 5) : 0);
  int stride = gridDim.x * (256 >> 6) * NSW;
  int nt   = lane & (TPN - 1);
  int c0   = nt * 8;
  int head = c0 / CH;
  int gl   = lane & (G - 1);
  int srcbase = (lane / G) * G;

  float a_prelu = ACT ? prelu_a[0] : 0.f;
  float4 bv0 = *(const float4*)&bias[c0];
  float4 bv1 = *(const float4*)&bias[c0 + 4];

  for (int node = slot0; node < n; node += stride) {
    int beg = rowptr[node];
    int cnt = rowptr[node + 1] - beg;
    float adv = ad[node * H + head];
    float denom = 0.f;
    float acc[8] = {};
    for (int b = 0; b < cnt; b += G) {
      int i = b + gl;
      float w = 0.f; int s = 0;
      if (i < cnt) {
        s = csr[beg + i];
        float v = as[s * H + head] + adv;
        v = (v >= 0.f) ? v : NEG_SLOPE * v;
        w = __expf(v);
      }
      denom += grp_sum<G>(w);
      int nedge = cnt - b; if (nedge > G) nedge = G;
      int kk = 0;
      for (; kk + 4 <= nedge; kk += 4) {
        int sj[4]; float wj[4]; H8 uj[4];
#pragma unroll
        for (int j = 0; j < 4; ++j) {
          sj[j] = __shfl(s, srcbase + kk + j);
          wj[j] = __shfl(w, srcbase + kk + j);
        }
#pragma unroll
        for (int j = 0; j < 4; ++j)
          uj[j].u4 = *(const uint4*)&h[(size_t)sj[j] * CT + c0];
#pragma unroll
        for (int j = 0; j < 4; ++j) {
#pragma unroll
          for (int q = 0; q < 8; ++q) acc[q] += wj[j] * (float)uj[j].f[q];
        }
      }
      {
        int rem = nedge - kk;
        int sj[3]; float wj[3]; H8 uj[3];
#pragma unroll
        for (int j = 0; j < 3; ++j) {
          if (j < rem) {
            sj[j] = __shfl(s, srcbase + kk + j);
            wj[j] = __shfl(w, srcbase + kk + j);
          }
        }
#pragma unroll
        for (int j = 0; j < 3; ++j)
          if (j < rem) uj[j].u4 = *(const uint4*)&h[(size_t)sj[j] * CT + c0];
#pragma unroll
        for (int j = 0; j < 3; ++j) {
          if (j < rem) {
#pragma unroll
            for (int q = 0; q < 8; ++q) acc[q] += wj[j] * (float)uj[j].f[q];
          }
        }
      }
    }

    float inv = 1.f / (denom + 1e-16f);
    float o[8];
    o[0] = acc[0] * inv + bv0.x; o[1] = acc[1] * inv + bv0.y;
    o[2] = acc[2] * inv + bv0.z; o[3] = acc[3] * inv + bv0.w;
    o[4] = acc[4] * inv + bv1.x; o[5] = acc[5] * inv + bv1.y;
    o[6] = acc[6] * inv + bv1.z; o[7] = acc[7] * inv + bv1.w;
    if (ACT) {
#pragma unroll
      for (int q = 0; q < 8; ++q) o[q] = (o[q] >= 0.f) ? o[q] : a_prelu * o[q];
    }
    if (WF) {
      *(float4*)&outf[(size_t)node * CT + c0]     = make_float4(o[0], o[1], o[2], o[3]);
      *(float4*)&outf[(size_t)node * CT + c0 + 4] = make_float4(o[4], o[5], o[6], o[7]);
    }
    if (WH) {
      H8 p;
#pragma unroll
      for (int q = 0; q < 8; ++q) p.f[q] = (_Float16)o[q];
      *(uint4*)&outh[(size_t)node * CT + c0] = p.u4;
    }
  }
}

// ================= launch =================
extern "C" void kernel_launch(void* const* d_in, const int* in_sizes, int n_in,
                              void* d_out, int out_size, void* d_ws, size_t ws_size,
                              hipStream_t stream) {
  const float* x      = (const float*)d_in[0];
  const int*   ei     = (const int*)d_in[1];
  const float* W1     = (const float*)d_in[2];
  const float* a_s1   = (const float*)d_in[3];
  const float* a_d1   = (const float*)d_in[4];
  const float* b1     = (const float*)d_in[5];
  const float* prelu  = (const float*)d_in[6];
  const float* W2     = (const float*)d_in[7];
  const float* a_s2   = (const float*)d_in[8];
  const float* a_d2   = (const float*)d_in[9];
  const float* b2     = (const float*)d_in[10];
  const float* Wd     = (const float*)d_in[11];
  const float* a_sd   = (const float*)d_in[12];
  const float* a_dd   = (const float*)d_in[13];
  const float* bd     = (const float*)d_in[14];

  const int N = in_sizes[0] / 256;   // 50000
  const int E = in_sizes[1] / 2;     // 400000
  const int* e_src = ei;
  const int* e_dst = ei + E;

  float* z    = (float*)d_out;           // N*256 fp32
  float* xhat = z + (size_t)N * 256;     // N*256 fp32

  // out1_h (layer-1 fp16 output, N*512 f16) lives in the xhat half of d_out:
  // dead after the layer-2 GEMM; xhat written only by the decoder's final agg.
  _Float16* out1_h = (_Float16*)xhat;

  // ---- workspace (~56 MB) ----
  char* wp = (char*)d_ws;
  auto alloc = [&](size_t bytes) { char* p = wp; wp += (bytes + 15) & ~(size_t)15; return p; };
  _Float16* h_h  = (_Float16*)alloc((size_t)N * 512 * 2);  // h1 / h2 / h3
  float* alpS    = (float*)alloc((size_t)N * 4 * 4);
  float* alpD    = (float*)alloc((size_t)N * 4 * 4);
  int* rowptr    = (int*)alloc((size_t)(N + 1) * 4);
  int* csr       = (int*)alloc((size_t)(E + N) * 4);
  int* cursor    = (int*)alloc((size_t)N * 4);
  int* counts    = (int*)alloc((size_t)N * 4);
  int* pref      = (int*)alloc((size_t)N * 4);
  int* bsum      = (int*)alloc((size_t)256 * 4);
  _Float16* Wt1  = (_Float16*)alloc((size_t)512 * 256 * 2);
  _Float16* Wt2  = (_Float16*)alloc((size_t)256 * 512 * 2);
  _Float16* Wtd  = (_Float16*)alloc((size_t)256 * 256 * 2);

  const int B = 256;
  const int gN = (N + B - 1) / B;
  const int gE = (E + B - 1) / B;
  const int AGG_GRID = 2048;   // persistent: 8 blocks/CU x 256 CU

  // ---- CSR (built once, reused for all 3 layers) ----
  k_init_counts<<<gN, B, 0, stream>>>(counts, N);
  k_hist<<<gE, B, 0, stream>>>(e_dst, counts, E);
  k_scan1<<<gN, B, 0, stream>>>(counts, pref, bsum, N);
  k_scan2<<<1, B, 0, stream>>>(bsum, gN);
  k_scan3<<<gN, B, 0, stream>>>(pref, bsum, rowptr, N);
  k_init_csr<<<gN, B, 0, stream>>>(rowptr, cursor, csr, N);
  k_fill<<<gE, B, 0, stream>>>(e_src, e_dst, cursor, csr, E);

  // ---- weight converts (fp32 KxN -> fp16 NxK) ----
  k_w2h<<<(256 * 512 + B - 1) / B, B, 0, stream>>>(W1, Wt1, 256, 512);
  k_w2h<<<(512 * 256 + B - 1) / B, B, 0, stream>>>(W2, Wt2, 512, 256);
  k_w2h<<<(256 * 256 + B - 1) / B, B, 0, stream>>>(Wd, Wtd, 256, 256);

  const int gy = (N + 255) / 256;

  // ---- layer 1: 256 -> 4x128 concat, PReLU ----
  {
    dim3 grid(512 / 128, gy);
    k_gemm_f16<true><<<grid, 512, 0, stream>>>(x, Wt1, h_h, N, 512, 256);
    int tot = N * 4;
    k_alpha<4, 128><<<(tot * 64 + B - 1) / B, B, 0, stream>>>(h_h, a_s1, a_d1, alpS, alpD, tot);
    k_agg<512, 4, 1, 0, 1><<<AGG_GRID, B, 0, stream>>>(
        h_h, alpS, alpD, rowptr, csr, b1, prelu, nullptr, out1_h, N);
  }

  // ---- layer 2: 512 -> 256, 1 head; writes z (fp32 in d_out) ----
  {
    dim3 grid(256 / 128, gy);
    k_gemm_f16<false><<<grid, 512, 0, stream>>>(out1_h, Wt2, h_h, N, 256, 512);
    k_alpha<1, 256><<<(N * 64 + B - 1) / B, B, 0, stream>>>(h_h, a_s2, a_d2, alpS, alpD, N);
    k_agg<256, 1, 0, 1, 0><<<AGG_GRID, B, 0, stream>>>(
        h_h, alpS, alpD, rowptr, csr, b2, prelu, z, nullptr, N);
  }

  // ---- decoder: 256 -> 256, 1 head; reads z (fp32), writes xhat ----
  {
    dim3 grid(256 / 128, gy);
    k_gemm_f16<true><<<grid, 512, 0, stream>>>(z, Wtd, h_h, N, 256, 256);
    k_alpha<1, 256><<<(N * 64 + B - 1) / B, B, 0, stream>>>(h_h, a_sd, a_dd, alpS, alpD, N);
    k_agg<256, 1, 0, 1, 0><<<AGG_GRID, B, 0, stream>>>(
        h_h, alpS, alpD, rowptr, csr, bd, prelu, xhat, nullptr, N);
  }
}

// Round 14
// 495.476 us; speedup vs baseline: 2.8497x; 1.0594x over previous
//
#include <hip/hip_runtime.h>
#include <hip/hip_bf16.h>
#include <cstdint>

#define NEG_SLOPE 0.2f

typedef _Float16 f16x8 __attribute__((ext_vector_type(8)));
typedef float f32x4 __attribute__((ext_vector_type(4)));

union H2 { uint32_t u; _Float16 f[2]; };
union H8 { uint4 u4; _Float16 f[8]; };

// ================= CSR build =================
__global__ void k_init_counts(int* __restrict__ counts, int n) {
  int i = blockIdx.x * blockDim.x + threadIdx.x;
  if (i < n) counts[i] = 1;  // self loop
}

__global__ void k_hist(const int* __restrict__ dst, int* __restrict__ counts, int e) {
  int i = blockIdx.x * blockDim.x + threadIdx.x;
  if (i < e) atomicAdd(&counts[dst[i]], 1);
}

// hierarchical scan
__global__ void k_scan1(const int* __restrict__ counts, int* __restrict__ pref,
                        int* __restrict__ bsum, int n) {
  __shared__ int sh[256];
  int tid = threadIdx.x;
  int i = blockIdx.x * 256 + tid;
  int v = (i < n) ? counts[i] : 0;
  sh[tid] = v;
  __syncthreads();
  for (int off = 1; off < 256; off <<= 1) {
    int t = (tid >= off) ? sh[tid - off] : 0;
    __syncthreads();
    sh[tid] += t;
    __syncthreads();
  }
  if (i < n) pref[i] = sh[tid];
  if (tid == 255) bsum[blockIdx.x] = sh[255];
}

__global__ void k_scan2(int* __restrict__ bsum, int nb) {
  __shared__ int sh[256];
  int tid = threadIdx.x;
  int v = (tid < nb) ? bsum[tid] : 0;
  sh[tid] = v;
  __syncthreads();
  for (int off = 1; off < 256; off <<= 1) {
    int t = (tid >= off) ? sh[tid - off] : 0;
    __syncthreads();
    sh[tid] += t;
    __syncthreads();
  }
  if (tid < nb) bsum[tid] = sh[tid];
}

__global__ void k_scan3(const int* __restrict__ pref, const int* __restrict__ bsum,
                        int* __restrict__ rowptr, int n) {
  int i = blockIdx.x * blockDim.x + threadIdx.x;
  if (i < n) rowptr[i + 1] = pref[i] + (blockIdx.x ? bsum[blockIdx.x - 1] : 0);
  if (i == 0) rowptr[0] = 0;
}

__global__ void k_init_csr(const int* __restrict__ rowptr, int* __restrict__ cursor,
                           int* __restrict__ csr_src, int n) {
  int i = blockIdx.x * blockDim.x + threadIdx.x;
  if (i < n) { int r = rowptr[i]; csr_src[r] = i; cursor[i] = r + 1; }
}

__global__ void k_fill(const int* __restrict__ src, const int* __restrict__ dst,
                       int* __restrict__ cursor, int* __restrict__ csr_src, int e) {
  int i = blockIdx.x * blockDim.x + threadIdx.x;
  if (i < e) { int p = atomicAdd(&cursor[dst[i]], 1); csr_src[p] = src[i]; }
}

__global__ void k_zero2(float* __restrict__ a, float* __restrict__ b, int n) {
  int i = blockIdx.x * blockDim.x + threadIdx.x;
  if (i < n) { a[i] = 0.f; b[i] = 0.f; }
}

// ================= weight convert: W (KxN fp32) -> Wt (NxK fp16) =================
__global__ void k_w2h(const float* __restrict__ W, _Float16* __restrict__ Wt, int K, int N) {
  int i = blockIdx.x * blockDim.x + threadIdx.x;
  if (i < K * N) {
    int k = i / N, n = i - k * N;
    Wt[(size_t)n * K + k] = (_Float16)W[i];
  }
}

// ====== fp16 MFMA GEMM + fused alpha epilogue ======
// C(f16) = A(MxK) @ Bt^T (Bt is NxK). BM=256, BN=128, BK=64. 512 thr = 8 waves.
// Epilogue also computes alpha_s/d[node,head] = sum_c h[node,head,c]*a[head,c].
// Since a_src is (H,CH) flattened to N, coefficient for global col cg is
// a_src[cg]. ALPHA_ATOMIC=false: block covers a full head (CH==BN) -> direct
// store. true: 2 blocks/head -> atomicAdd into pre-zeroed buffers.
template <bool A_F32, int H, bool ALPHA_ATOMIC>
__global__ __launch_bounds__(512) void k_gemm_f16(
    const void* __restrict__ Av, const _Float16* __restrict__ Bt,
    _Float16* __restrict__ C, const float* __restrict__ aS,
    const float* __restrict__ aD, float* __restrict__ alpS,
    float* __restrict__ alpD, int M, int N, int K) {
  __shared__ _Float16 As[256 * 72];
  __shared__ _Float16 Bs[128 * 72];
  const int tid  = threadIdx.x;
  const int lane = tid & 63;
  const int wid  = tid >> 6;
  const int wm = wid >> 1;
  const int wn = wid & 1;
  const int row0 = blockIdx.y * 256, col0 = blockIdx.x * 128;
  const int l15 = lane & 15, l16 = lane >> 4;
  const int srow = tid >> 3;
  const int skc  = (tid & 7) * 8;

  f32x4 acc[4][4] = {};

  for (int k0 = 0; k0 < K; k0 += 64) {
#pragma unroll
    for (int p = 0; p < 4; ++p) {
      int r = p * 64 + srow;
      int gr = row0 + r; if (gr > M - 1) gr = M - 1;
      _Float16 tmp[8];
      if constexpr (A_F32) {
        const float* src = (const float*)Av + (size_t)gr * K + k0 + skc;
        float4 v0 = ((const float4*)src)[0];
        float4 v1 = ((const float4*)src)[1];
        tmp[0] = (_Float16)v0.x; tmp[1] = (_Float16)v0.y;
        tmp[2] = (_Float16)v0.z; tmp[3] = (_Float16)v0.w;
        tmp[4] = (_Float16)v1.x; tmp[5] = (_Float16)v1.y;
        tmp[6] = (_Float16)v1.z; tmp[7] = (_Float16)v1.w;
      } else {
        const _Float16* src = (const _Float16*)Av + (size_t)gr * K + k0 + skc;
        *(uint4*)tmp = *(const uint4*)src;
      }
      *(uint4*)&As[r * 72 + skc] = *(uint4*)tmp;
    }
#pragma unroll
    for (int p = 0; p < 2; ++p) {
      int nr_ = p * 64 + srow;
      const _Float16* src = Bt + (size_t)(col0 + nr_) * K + k0 + skc;
      *(uint4*)&Bs[nr_ * 72 + skc] = *(const uint4*)src;
    }
    __syncthreads();
#pragma unroll
    for (int ks = 0; ks < 2; ++ks) {
      f16x8 bfrag[4];
#pragma unroll
      for (int nr = 0; nr < 4; ++nr)
        bfrag[nr] = *(const f16x8*)&Bs[(wn * 64 + nr * 16 + l15) * 72 + ks * 32 + l16 * 8];
#pragma unroll
      for (int mr = 0; mr < 4; ++mr) {
        f16x8 afrag = *(const f16x8*)&As[(wm * 64 + mr * 16 + l15) * 72 + ks * 32 + l16 * 8];
#pragma unroll
        for (int nr = 0; nr < 4; ++nr)
          acc[mr][nr] = __builtin_amdgcn_mfma_f32_16x16x32_f16(afrag, bfrag[nr], acc[mr][nr], 0, 0, 0);
      }
    }
    __syncthreads();
  }

  // ---- C store (fp16, rounded) ----
#pragma unroll
  for (int mr = 0; mr < 4; ++mr) {
#pragma unroll
    for (int j = 0; j < 4; ++j) {
      int rg = row0 + wm * 64 + mr * 16 + l16 * 4 + j;
      if (rg < M) {
#pragma unroll
        for (int nr = 0; nr < 4; ++nr) {
          int cg = col0 + wn * 64 + nr * 16 + l15;
          C[(size_t)rg * N + cg] = (_Float16)acc[mr][nr][j];
        }
      }
    }
  }

  // ---- fused alpha epilogue ----
  float avs[4], avd[4];
#pragma unroll
  for (int nr = 0; nr < 4; ++nr) {
    int cg = col0 + wn * 64 + nr * 16 + l15;
    avs[nr] = aS[cg];
    avd[nr] = aD[cg];
  }
  float* alp = (float*)As;  // reuse LDS: [2 wn][256 rows][2]
#pragma unroll
  for (int mr = 0; mr < 4; ++mr) {
#pragma unroll
    for (int j = 0; j < 4; ++j) {
      float hs = 0.f, hd = 0.f;
#pragma unroll
      for (int nr = 0; nr < 4; ++nr) {
        float v = (float)(_Float16)acc[mr][nr][j];  // match h_h rounding
        hs += v * avs[nr];
        hd += v * avd[nr];
      }
#pragma unroll
      for (int o = 1; o < 16; o <<= 1) {
        hs += __shfl_xor(hs, o);
        hd += __shfl_xor(hd, o);
      }
      if (l15 == 0) {
        int r = wm * 64 + mr * 16 + l16 * 4 + j;
        alp[(wn * 256 + r) * 2 + 0] = hs;
        alp[(wn * 256 + r) * 2 + 1] = hd;
      }
    }
  }
  __syncthreads();
  if (tid < 256) {
    int rg = row0 + tid;
    if (rg < M) {
      float s_ = alp[tid * 2 + 0] + alp[(256 + tid) * 2 + 0];
      float d_ = alp[tid * 2 + 1] + alp[(256 + tid) * 2 + 1];
      int head = (int)((long)col0 * H / N);
      if (ALPHA_ATOMIC) {
        atomicAdd(&alpS[rg * H + head], s_);
        atomicAdd(&alpD[rg * H + head], d_);
      } else {
        alpS[rg * H + head] = s_;
        alpD[rg * H + head] = d_;
      }
    }
  }
}

// ====== fused softmax + aggregation, persistent grid-stride waves ======
template <int W>
__device__ __forceinline__ float grp_sum(float v) {
#pragma unroll
  for (int o = W / 2; o; o >>= 1) v += __shfl_xor(v, o);
  return v;
}

template <int CT, int H, int ACT, int WF, int WH>
__global__ __launch_bounds__(256) void k_agg(
    const _Float16* __restrict__ h, const float* __restrict__ as,
    const float* __restrict__ ad, const int* __restrict__ rowptr,
    const int* __restrict__ csr, const float* __restrict__ bias,
    const float* __restrict__ prelu_a, float* __restrict__ outf,
    _Float16* __restrict__ outh, int n) {
  constexpr int CH  = CT / H;
  constexpr int TPN = CT / 8;       // threads per node: 64 (CT=512) / 32 (CT=256)
  constexpr int NSW = 64 / TPN;     // nodes per wave: 1 / 2
  constexpr int G   = CH / 8;       // lanes per (node,head) group: 16 / 32

  int lane = threadIdx.x & 63;
  int wib  = threadIdx.x >> 6;
  int slot0  = (blockIdx.x * (256 >> 6) + wib) * NSW + ((NSW == 2) ? (lane >> 5) : 0);
  int stride = gridDim.x * (256 >> 6) * NSW;
  int nt   = lane & (TPN - 1);
  int c0   = nt * 8;
  int head = c0 / CH;
  int gl   = lane & (G - 1);
  int srcbase = (lane / G) * G;

  float a_prelu = ACT ? prelu_a[0] : 0.f;
  float4 bv0 = *(const float4*)&bias[c0];
  float4 bv1 = *(const float4*)&bias[c0 + 4];

  for (int node = slot0; node < n; node += stride) {
    int beg = rowptr[node];
    int cnt = rowptr[node + 1] - beg;
    float adv = ad[node * H + head];
    float denom = 0.f;
    float acc[8] = {};
    for (int b = 0; b < cnt; b += G) {
      int i = b + gl;
      float w = 0.f; int s = 0;
      if (i < cnt) {
        s = csr[beg + i];
        float v = as[s * H + head] + adv;
        v = (v >= 0.f) ? v : NEG_SLOPE * v;
        w = __expf(v);
      }
      denom += grp_sum<G>(w);
      int nedge = cnt - b; if (nedge > G) nedge = G;
      int kk = 0;
      for (; kk + 4 <= nedge; kk += 4) {
        int sj[4]; float wj[4]; H8 uj[4];
#pragma unroll
        for (int j = 0; j < 4; ++j) {
          sj[j] = __shfl(s, srcbase + kk + j);
          wj[j] = __shfl(w, srcbase + kk + j);
        }
#pragma unroll
        for (int j = 0; j < 4; ++j)
          uj[j].u4 = *(const uint4*)&h[(size_t)sj[j] * CT + c0];
#pragma unroll
        for (int j = 0; j < 4; ++j) {
#pragma unroll
          for (int q = 0; q < 8; ++q) acc[q] += wj[j] * (float)uj[j].f[q];
        }
      }
      {
        int rem = nedge - kk;
        int sj[3]; float wj[3]; H8 uj[3];
#pragma unroll
        for (int j = 0; j < 3; ++j) {
          if (j < rem) {
            sj[j] = __shfl(s, srcbase + kk + j);
            wj[j] = __shfl(w, srcbase + kk + j);
          }
        }
#pragma unroll
        for (int j = 0; j < 3; ++j)
          if (j < rem) uj[j].u4 = *(const uint4*)&h[(size_t)sj[j] * CT + c0];
#pragma unroll
        for (int j = 0; j < 3; ++j) {
          if (j < rem) {
#pragma unroll
            for (int q = 0; q < 8; ++q) acc[q] += wj[j] * (float)uj[j].f[q];
          }
        }
      }
    }

    float inv = 1.f / (denom + 1e-16f);
    float o[8];
    o[0] = acc[0] * inv + bv0.x; o[1] = acc[1] * inv + bv0.y;
    o[2] = acc[2] * inv + bv0.z; o[3] = acc[3] * inv + bv0.w;
    o[4] = acc[4] * inv + bv1.x; o[5] = acc[5] * inv + bv1.y;
    o[6] = acc[6] * inv + bv1.z; o[7] = acc[7] * inv + bv1.w;
    if (ACT) {
#pragma unroll
      for (int q = 0; q < 8; ++q) o[q] = (o[q] >= 0.f) ? o[q] : a_prelu * o[q];
    }
    if (WF) {
      *(float4*)&outf[(size_t)node * CT + c0]     = make_float4(o[0], o[1], o[2], o[3]);
      *(float4*)&outf[(size_t)node * CT + c0 + 4] = make_float4(o[4], o[5], o[6], o[7]);
    }
    if (WH) {
      H8 p;
#pragma unroll
      for (int q = 0; q < 8; ++q) p.f[q] = (_Float16)o[q];
      *(uint4*)&outh[(size_t)node * CT + c0] = p.u4;
    }
  }
}

// ================= launch =================
extern "C" void kernel_launch(void* const* d_in, const int* in_sizes, int n_in,
                              void* d_out, int out_size, void* d_ws, size_t ws_size,
                              hipStream_t stream) {
  const float* x      = (const float*)d_in[0];
  const int*   ei     = (const int*)d_in[1];
  const float* W1     = (const float*)d_in[2];
  const float* a_s1   = (const float*)d_in[3];
  const float* a_d1   = (const float*)d_in[4];
  const float* b1     = (const float*)d_in[5];
  const float* prelu  = (const float*)d_in[6];
  const float* W2     = (const float*)d_in[7];
  const float* a_s2   = (const float*)d_in[8];
  const float* a_d2   = (const float*)d_in[9];
  const float* b2     = (const float*)d_in[10];
  const float* Wd     = (const float*)d_in[11];
  const float* a_sd   = (const float*)d_in[12];
  const float* a_dd   = (const float*)d_in[13];
  const float* bd     = (const float*)d_in[14];

  const int N = in_sizes[0] / 256;   // 50000
  const int E = in_sizes[1] / 2;     // 400000
  const int* e_src = ei;
  const int* e_dst = ei + E;

  float* z    = (float*)d_out;           // N*256 fp32
  float* xhat = z + (size_t)N * 256;     // N*256 fp32

  // out1_h (layer-1 fp16 output, N*512 f16) lives in the xhat half of d_out:
  // dead after the layer-2 GEMM; xhat written only by the decoder's final agg.
  _Float16* out1_h = (_Float16*)xhat;

  // ---- workspace (~56 MB) ----
  char* wp = (char*)d_ws;
  auto alloc = [&](size_t bytes) { char* p = wp; wp += (bytes + 15) & ~(size_t)15; return p; };
  _Float16* h_h  = (_Float16*)alloc((size_t)N * 512 * 2);  // h1 / h2 / h3
  float* alpS    = (float*)alloc((size_t)N * 4 * 4);
  float* alpD    = (float*)alloc((size_t)N * 4 * 4);
  int* rowptr    = (int*)alloc((size_t)(N + 1) * 4);
  int* csr       = (int*)alloc((size_t)(E + N) * 4);
  int* cursor    = (int*)alloc((size_t)N * 4);
  int* counts    = (int*)alloc((size_t)N * 4);
  int* pref      = (int*)alloc((size_t)N * 4);
  int* bsum      = (int*)alloc((size_t)256 * 4);
  _Float16* Wt1  = (_Float16*)alloc((size_t)512 * 256 * 2);
  _Float16* Wt2  = (_Float16*)alloc((size_t)256 * 512 * 2);
  _Float16* Wtd  = (_Float16*)alloc((size_t)256 * 256 * 2);

  const int B = 256;
  const int gN = (N + B - 1) / B;
  const int gE = (E + B - 1) / B;
  const int AGG_GRID = 2048;   // persistent: 8 blocks/CU x 256 CU

  // ---- CSR (built once, reused for all 3 layers) ----
  k_init_counts<<<gN, B, 0, stream>>>(counts, N);
  k_hist<<<gE, B, 0, stream>>>(e_dst, counts, E);
  k_scan1<<<gN, B, 0, stream>>>(counts, pref, bsum, N);
  k_scan2<<<1, B, 0, stream>>>(bsum, gN);
  k_scan3<<<gN, B, 0, stream>>>(pref, bsum, rowptr, N);
  k_init_csr<<<gN, B, 0, stream>>>(rowptr, cursor, csr, N);
  k_fill<<<gE, B, 0, stream>>>(e_src, e_dst, cursor, csr, E);

  // ---- weight converts (fp32 KxN -> fp16 NxK) ----
  k_w2h<<<(256 * 512 + B - 1) / B, B, 0, stream>>>(W1, Wt1, 256, 512);
  k_w2h<<<(512 * 256 + B - 1) / B, B, 0, stream>>>(W2, Wt2, 512, 256);
  k_w2h<<<(256 * 256 + B - 1) / B, B, 0, stream>>>(Wd, Wtd, 256, 256);

  const int gy = (N + 255) / 256;

  // ---- layer 1: 256 -> 4x128 concat, PReLU; alpha fused (direct store) ----
  {
    dim3 grid(512 / 128, gy);
    k_gemm_f16<true, 4, false><<<grid, 512, 0, stream>>>(
        x, Wt1, h_h, a_s1, a_d1, alpS, alpD, N, 512, 256);
    k_agg<512, 4, 1, 0, 1><<<AGG_GRID, B, 0, stream>>>(
        h_h, alpS, alpD, rowptr, csr, b1, prelu, nullptr, out1_h, N);
  }

  // ---- layer 2: 512 -> 256, 1 head; alpha fused (atomic, pre-zeroed) ----
  {
    k_zero2<<<gN, B, 0, stream>>>(alpS, alpD, N);
    dim3 grid(256 / 128, gy);
    k_gemm_f16<false, 1, true><<<grid, 512, 0, stream>>>(
        out1_h, Wt2, h_h, a_s2, a_d2, alpS, alpD, N, 256, 512);
    k_agg<256, 1, 0, 1, 0><<<AGG_GRID, B, 0, stream>>>(
        h_h, alpS, alpD, rowptr, csr, b2, prelu, z, nullptr, N);
  }

  // ---- decoder: 256 -> 256, 1 head; alpha fused (atomic, pre-zeroed) ----
  {
    k_zero2<<<gN, B, 0, stream>>>(alpS, alpD, N);
    dim3 grid(256 / 128, gy);
    k_gemm_f16<true, 1, true><<<grid, 512, 0, stream>>>(
        z, Wtd, h_h, a_sd, a_dd, alpS, alpD, N, 256, 256);
    k_agg<256, 1, 0, 1, 0><<<AGG_GRID, B, 0, stream>>>(
        h_h, alpS, alpD, rowptr, csr, bd, prelu, xhat, nullptr, N);
  }
}